// Round 11
// baseline (217.659 us; speedup 1.0000x reference)
//
#include <hip/hip_runtime.h>
#include <math.h>

typedef _Float16 f16x8 __attribute__((ext_vector_type(8)));
typedef _Float16 f16x4 __attribute__((ext_vector_type(4)));
typedef float f32x4 __attribute__((ext_vector_type(4)));

#define NSEQ   128
#define DIMH   64
#define NHEAD  8
#define DMODEL 512
#define SCALE  0.125f      // 64^-0.5
#define SPAD   136         // f16 elems per PT row (272B: odd 16B-quads -> fragPT conflict-free)

// ws layout (float offsets)
#define OFF_X    0          // [32][128][64]
#define OFF_Y    262144
#define OFF_V    524288
#define OFF_COST 786432     // [32][128][128]
#define OFF_SWDS 1310720    // fast: [1024][2] (m_b, Z_b); fallback: [32][64] swds
#define OFF_W    1312768    // [32][64] (fallback only)
#define OFF_OH   1314816    // [4*128][512] f32 oh (fallback path)
#define OFF_XT   1576960    // [32][64][128]  X^T per head (dead after k_sortden)
#define OFF_YT   1839104    // [32][64][128]
#define OFF_ST   2101248    // [4096][384]  state: s(128), ss(128), inv(128) per build
#define OFF_PART 3674112    // partials: 1024 x 16384 (f16 -> 32MB, f32 -> 64MB)
#define END_PART 12062720   // = OFF_PART + 1024*16384/2 (f16 partial layout end)
// f16 alias: ohh = XT+131072 (written by k_avr after XT dead, read by k_out_f)

#define PF_SMEM  (NSEQ * SPAD * 2 + (768 + 8) * 4)               // 37920B -> 4 blocks/CU
#define PH_SMEM  (2 * NSEQ * SPAD * 2 + (128 * 3 + 512 + 8) * 4) // fallback

__device__ __forceinline__ f16x8 cvt8(f32x4 a, f32x4 b) {
  f16x8 h;
  h[0] = (_Float16)a[0]; h[1] = (_Float16)a[1]; h[2] = (_Float16)a[2]; h[3] = (_Float16)a[3];
  h[4] = (_Float16)b[0]; h[5] = (_Float16)b[1]; h[6] = (_Float16)b[2]; h[7] = (_Float16)b[3];
  return h;
}

// ------- K1: qkv = x @ w_qkv^T via MFMA, f32->f16 cvt fused into staging -------
__global__ __launch_bounds__(256) void k_qkv_f(const float* __restrict__ x,
                                               const float* __restrict__ wq,
                                               float* __restrict__ ws) {
  __shared__ _Float16 Ah[64][72];
  __shared__ _Float16 Bh[64][72];
  const int r0 = blockIdx.x * 64, c0 = blockIdx.y * 64;
  const int t = threadIdx.x, w = t >> 6, lane = t & 63;
  const int srow = t >> 2, sk = (t & 3) << 4;
  f32x4 acc[4] = {};
  for (int kc = 0; kc < 512; kc += 64) {
    __syncthreads();
    {
      const float* ap = &x[(size_t)(r0 + srow) * 512 + kc + sk];
      const float* bp = &wq[(size_t)(c0 + srow) * 512 + kc + sk];
      f32x4 a0 = *(const f32x4*)&ap[0], a1 = *(const f32x4*)&ap[4];
      f32x4 a2 = *(const f32x4*)&ap[8], a3 = *(const f32x4*)&ap[12];
      f32x4 b0 = *(const f32x4*)&bp[0], b1 = *(const f32x4*)&bp[4];
      f32x4 b2 = *(const f32x4*)&bp[8], b3 = *(const f32x4*)&bp[12];
      *(f16x8*)&Ah[srow][sk]     = cvt8(a0, a1);
      *(f16x8*)&Ah[srow][sk + 8] = cvt8(a2, a3);
      *(f16x8*)&Bh[srow][sk]     = cvt8(b0, b1);
      *(f16x8*)&Bh[srow][sk + 8] = cvt8(b2, b3);
    }
    __syncthreads();
#pragma unroll
    for (int k0 = 0; k0 < 64; k0 += 32) {
      f16x8 a = *(const f16x8*)&Ah[(w << 4) + (lane & 15)][k0 + ((lane >> 4) << 3)];
#pragma unroll
      for (int fj = 0; fj < 4; ++fj) {
        f16x8 b = *(const f16x8*)&Bh[(fj << 4) + (lane & 15)][k0 + ((lane >> 4) << 3)];
        acc[fj] = __builtin_amdgcn_mfma_f32_16x16x32_f16(a, b, acc[fj], 0, 0, 0);
      }
    }
  }
  float* X = ws + OFF_X; float* Y = ws + OFF_Y; float* V = ws + OFF_V;
  float* XT = ws + OFF_XT; float* YT = ws + OFF_YT;
  const int rowb = r0 + (w << 4) + ((lane >> 4) << 2);
#pragma unroll
  for (int fj = 0; fj < 4; ++fj) {
    const int c = c0 + (fj << 4) + (lane & 15);
    const int which = c >> 9, cc = c & 511, h = cc >> 6, d = cc & 63;
#pragma unroll
    for (int r = 0; r < 4; ++r) {
      const int rr = rowb + r, bb = rr >> 7, n = rr & 127;
      const int bh = bb * NHEAD + h;
      float val = acc[fj][r];
      size_t dst = ((size_t)bh * NSEQ + n) * DIMH + d;
      size_t dstT = ((size_t)bh * DIMH + d) * NSEQ + n;
      if (which == 0)      { X[dst] = val * SCALE; XT[dstT] = val * SCALE; }
      else if (which == 1) { Y[dst] = val * SCALE; YT[dstT] = val * SCALE; }
      else                 V[dst] = val;
    }
  }
}

// ---------------- K1-fallback: f32 VALU qkv ----------------
__global__ __launch_bounds__(256) void k_qkv(const float* __restrict__ x,
                                             const float* __restrict__ wqkv,
                                             float* __restrict__ ws, int wrT) {
  __shared__ float xs[64][65];
  __shared__ float wsm[64][65];
  const int r0 = blockIdx.x * 64;
  const int c0 = blockIdx.y * 64;
  const int t = threadIdx.x;
  const int tr = (t >> 4) << 2;
  const int tc = (t & 15) << 2;
  float acc[4][4] = {};
  for (int k0 = 0; k0 < 512; k0 += 64) {
    for (int idx = t; idx < 64 * 64; idx += 256) {
      int i = idx >> 6, j = idx & 63;
      xs[i][j]  = x[(size_t)(r0 + i) * 512 + k0 + j];
      wsm[i][j] = wqkv[(size_t)(c0 + i) * 512 + k0 + j];
    }
    __syncthreads();
    for (int kk = 0; kk < 64; ++kk) {
      float a[4], b[4];
#pragma unroll
      for (int u = 0; u < 4; ++u) { a[u] = xs[tr + u][kk]; b[u] = wsm[tc + u][kk]; }
#pragma unroll
      for (int u = 0; u < 4; ++u)
#pragma unroll
        for (int w = 0; w < 4; ++w) acc[u][w] += a[u] * b[w];
    }
    __syncthreads();
  }
  float* X = ws + OFF_X; float* Y = ws + OFF_Y; float* V = ws + OFF_V;
  float* XT = ws + OFF_XT; float* YT = ws + OFF_YT;
#pragma unroll
  for (int u = 0; u < 4; ++u) {
    int r = r0 + tr + u; int b = r >> 7, n = r & 127;
#pragma unroll
    for (int w = 0; w < 4; ++w) {
      int c = c0 + tc + w;
      float val = acc[u][w];
      int which = c >> 9;
      int cc = c & 511;
      int h = cc >> 6, d = cc & 63;
      int bh = b * NHEAD + h;
      size_t dst = ((size_t)bh * NSEQ + n) * DIMH + d;
      size_t dstT = ((size_t)bh * DIMH + d) * NSEQ + n;
      if (which == 0)      { X[dst] = val * SCALE; if (wrT) XT[dstT] = val * SCALE; }
      else if (which == 1) { Y[dst] = val * SCALE; if (wrT) YT[dstT] = val * SCALE; }
      else                 V[dst] = val;
    }
  }
}

// ---------------- K2: cost[bh][i][j] = ||X_i - Y_j||_2 ----------------
__global__ __launch_bounds__(256) void k_cost(float* __restrict__ ws) {
  __shared__ float Ys[128 * 64];
  __shared__ float Xs[16 * 64];
  __shared__ float xx[16], yy[128];
  const int bh = blockIdx.x, g = blockIdx.y;
  const int t = threadIdx.x;
  const float* Xg = ws + OFF_X + (size_t)bh * NSEQ * DIMH + (size_t)g * 16 * DIMH;
  const float* Yg = ws + OFF_Y + (size_t)bh * NSEQ * DIMH;
  for (int c = t; c < 1024; c += 256) Xs[c] = Xg[c];
  for (int c = t; c < 8192; c += 256) Ys[c] = Yg[c];
  __syncthreads();
  if (t < 128) {
    float s = 0;
    const f32x4* y4 = (const f32x4*)&Ys[t * 64];
#pragma unroll
    for (int d = 0; d < 16; ++d) { f32x4 v = y4[d]; s += v[0]*v[0]+v[1]*v[1]+v[2]*v[2]+v[3]*v[3]; }
    yy[t] = s;
  } else if (t < 144) {
    int i = t - 128; float s = 0;
    const f32x4* x4 = (const f32x4*)&Xs[i * 64];
#pragma unroll
    for (int d = 0; d < 16; ++d) { f32x4 v = x4[d]; s += v[0]*v[0]+v[1]*v[1]+v[2]*v[2]+v[3]*v[3]; }
    xx[i] = s;
  }
  __syncthreads();
  const int i = t >> 4, j0 = (t & 15) << 3;
  f32x4 xr[16];
#pragma unroll
  for (int d = 0; d < 16; ++d) xr[d] = ((const f32x4*)&Xs[i * 64])[d];
  const float xxi = xx[i];
  float* C = ws + OFF_COST + (size_t)bh * NSEQ * NSEQ + (size_t)(g * 16 + i) * NSEQ + j0;
  f32x4 o0, o1;
#pragma unroll
  for (int jj = 0; jj < 8; ++jj) {
    const f32x4* y4 = (const f32x4*)&Ys[(j0 + jj) * 64];
    float dot = 0;
#pragma unroll
    for (int d = 0; d < 16; ++d) {
      f32x4 xv = xr[d], yv = y4[d];
      dot += xv[0]*yv[0] + xv[1]*yv[1] + xv[2]*yv[2] + xv[3]*yv[3];
    }
    float sq = xxi + yy[j0 + jj] - 2.f * dot;
    float cv = sqrtf(fmaxf(sq, 0.f));
    if (jj < 4) o0[jj] = cv; else o1[jj - 4] = cv;
  }
  *(f32x4*)&C[0] = o0;
  *(f32x4*)&C[4] = o1;
}

// -------- K_sortden: per (bh,l,uv) compute state s(128), ss(128), inv(128) --------
__global__ __launch_bounds__(256) void k_sortden(float* __restrict__ ws) {
  __shared__ float s_lds[128], ss_lds[128], den2[256];
  const int bid = blockIdx.x;            // (bh*64 + l)*2 + uv
  const int t = threadIdx.x;
  const float* src = ws + ((bid & 1) ? OFF_YT : OFF_XT) + (size_t)(bid >> 1) * NSEQ;
  float* st = ws + OFF_ST + (size_t)bid * 384;
  if (t < 128) s_lds[t] = src[t];
  __syncthreads();
  if (t < 128) {
    const float v = s_lds[t];
    int rank = 0;
#pragma unroll 4
    for (int m = 0; m < NSEQ; m += 4) {
      f32x4 u = *(const f32x4*)&s_lds[m];
#pragma unroll
      for (int j = 0; j < 4; ++j)
        rank += (u[j] > v) || (u[j] == v && (m + j) < t);
    }
    ss_lds[rank] = v;   // descending sorted
  }
  __syncthreads();
  {
    const int k = t & 127, half = t >> 7;
    const float sk = ss_lds[k];
    const float* sb = s_lds + (half << 6);
    float sum = 0.f;
#pragma unroll 4
    for (int m = 0; m < 64; m += 4) {
      f32x4 u = *(const f32x4*)&sb[m];
#pragma unroll
      for (int j = 0; j < 4; ++j) {
        float d = u[j] - sk;
        sum += __expf(-1000.f * d * d);
      }
    }
    den2[(half << 7) + k] = sum;
  }
  __syncthreads();
  if (t < 128) {
    st[t]       = s_lds[t];
    st[128 + t] = ss_lds[t];
    st[256 + t] = 1.f / (den2[t] + den2[128 + t]);
  }
}

// Generate PT entries from LDS state (512 threads; no internal barrier).
// Mapping i=t&127, k0=(t>>7)*32: ss/inv reads are wave-uniform (broadcast,
// conflict-free); PT writes stride 272B -> spread across bank quads. (The old
// i=t>>2 mapping made every ss/inv f32x4 read a 4-way same-quad conflict.)
__device__ __forceinline__ void gen_PT(const float* __restrict__ st,
                                       _Float16* __restrict__ PT, int t) {
  const int i = t & 127, k0 = (t >> 7) << 5;
  const float si = st[i];
  const float* ssp = st + 128 + k0;
  const float* ivp = st + 256 + k0;
#pragma unroll
  for (int kb = 0; kb < 32; kb += 8) {
    f32x4 sv0 = *(const f32x4*)&ssp[kb];
    f32x4 sv1 = *(const f32x4*)&ssp[kb + 4];
    f32x4 iv0 = *(const f32x4*)&ivp[kb];
    f32x4 iv1 = *(const f32x4*)&ivp[kb + 4];
    f16x8 pk;
#pragma unroll
    for (int j = 0; j < 4; ++j) {
      float d0 = si - sv0[j];
      float d1 = si - sv1[j];
      pk[j]     = (_Float16)(__expf(-1000.f * d0 * d0) * iv0[j]);
      pk[j + 4] = (_Float16)(__expf(-1000.f * d1 * d1) * iv1[j]);
    }
    *reinterpret_cast<f16x8*>(&PT[i * SPAD + k0 + kb]) = pk;
  }
}

// Per-lane A-fragment gen: 8 entries for row (r0+lane&15), k..k+8
__device__ __forceinline__ f16x8 gen_Afrag(float si, const float* __restrict__ ss,
                                           const float* __restrict__ iv, int k) {
  f32x4 s0 = *(const f32x4*)&ss[k], s1 = *(const f32x4*)&ss[k + 4];
  f32x4 i0 = *(const f32x4*)&iv[k], i1 = *(const f32x4*)&iv[k + 4];
  f16x8 a;
#pragma unroll
  for (int j = 0; j < 4; ++j) {
    float d0 = si - s0[j];
    float d1 = si - s1[j];
    a[j]     = (_Float16)(__expf(-1000.f * d0 * d0) * i0[j]);
    a[j + 4] = (_Float16)(__expf(-1000.f * d1 * d1) * i1[j]);
  }
  return a;
}

// Fallback: full in-kernel build, 512 threads, internal barriers.
__device__ void build_PT(const float* __restrict__ col, _Float16* __restrict__ PT,
                         float* s_, float* ss_, float* inv_, float* den4, int t) {
  if (t < NSEQ) s_[t] = col[(size_t)t * DIMH];
  __syncthreads();
  if (t < NSEQ) {
    const float v = s_[t];
    int rank = 0;
#pragma unroll 4
    for (int m = 0; m < NSEQ; m += 4) {
      f32x4 u = *(const f32x4*)&s_[m];
#pragma unroll
      for (int j = 0; j < 4; ++j)
        rank += (u[j] > v) || (u[j] == v && (m + j) < t);
    }
    ss_[rank] = v;
  }
  __syncthreads();
  {
    const int k = t & 127, q = t >> 7;
    const float sk = ss_[k];
    const float* sb = s_ + (q << 5);
    float sum = 0.f;
#pragma unroll 4
    for (int m = 0; m < 32; m += 4) {
      f32x4 u = *(const f32x4*)&sb[m];
#pragma unroll
      for (int j = 0; j < 4; ++j) {
        float d = u[j] - sk;
        sum += __expf(-1000.f * d * d);
      }
    }
    den4[(q << 7) + k] = sum;
  }
  __syncthreads();
  if (t < NSEQ)
    inv_[t] = 1.f / (den4[t] + den4[128 + t] + den4[256 + t] + den4[384 + t]);
  __syncthreads();
  {
    const int i = t >> 2, k0 = (t & 3) << 5;
    const float si = s_[i];
#pragma unroll
    for (int kb = 0; kb < 32; kb += 8) {
      f32x4 sv0 = *(const f32x4*)&ss_[k0 + kb];
      f32x4 sv1 = *(const f32x4*)&ss_[k0 + kb + 4];
      f32x4 iv0 = *(const f32x4*)&inv_[k0 + kb];
      f32x4 iv1 = *(const f32x4*)&inv_[k0 + kb + 4];
      f16x8 pk;
#pragma unroll
      for (int j = 0; j < 4; ++j) {
        float d0 = si - sv0[j];
        float d1 = si - sv1[j];
        pk[j]     = (_Float16)(__expf(-1000.f * d0 * d0) * iv0[j]);
        pk[j + 4] = (_Float16)(__expf(-1000.f * d1 * d1) * iv1[j]);
      }
      *reinterpret_cast<f16x8*>(&PT[i * SPAD + k0 + kb]) = pk;
    }
  }
  __syncthreads();
}

__device__ __forceinline__ f16x8 fragPT(const _Float16* PT, int baserow, int k0, int lane) {
  return *reinterpret_cast<const f16x8*>(
      &PT[(baserow + (lane & 15)) * SPAD + k0 + ((lane >> 4) << 3)]);
}

// ---- K_pf: fused phases — per block (bh, 2 l's): Gamma via MFMA, swds dot,
// ---- ONLINE softmax-weighted accumulation. 1024 blocks -> 4 blocks/CU. ----
template <bool HALFP>
__global__ __launch_bounds__(512, 8) void k_pf(float* __restrict__ ws) {
  extern __shared__ char smem[];
  _Float16* PvT = (_Float16*)smem;
  float* aux = (float*)(PvT + NSEQ * SPAD);   // 768 state
  float* red = aux + 768;                     // 8
  const int blk = blockIdx.x, bh = blk >> 5, lc = blk & 31;  // 2 l's per block
  const int t = threadIdx.x, w = t >> 6, lane = t & 63;
  const int r0 = w << 4;
  const int kq = (lane >> 4) << 3;
  const float* C = ws + OFF_COST + (size_t)bh * NSEQ * NSEQ;
  const int cr = r0 + ((lane >> 4) << 2), cc = lane & 15;
  f32x4 att[8];
#pragma unroll
  for (int b = 0; b < 8; ++b) att[b] = 0;
  float m_run = 3.0e38f, Z = 0.f;
  {   // initial state load
    const float* stg = ws + OFF_ST + (size_t)(bh * 64 + lc * 2) * 768;
    aux[t] = stg[t];
    if (t < 256) aux[t + 512] = stg[t + 512];
  }
  for (int q = 0; q < 2; ++q) {
    __syncthreads();             // aux ready
    gen_PT(aux + 384, PvT, t);
    __syncthreads();             // PvT ready
    const float si = aux[r0 + (lane & 15)];
    const float* ssu = aux + 128;
    const float* ivu = aux + 256;
    f32x4 acc[8];
#pragma unroll
    for (int b = 0; b < 8; ++b) acc[b] = 0;
#pragma unroll
    for (int kc = 0; kc < 4; ++kc) {
      const int k0 = kc << 5;
      f16x8 a = gen_Afrag(si, ssu, ivu, k0 + kq);
#pragma unroll
      for (int fj = 0; fj < 8; ++fj) {
        f16x8 b = fragPT(PvT, fj << 4, k0, lane);
        acc[fj] = __builtin_amdgcn_mfma_f32_16x16x32_f16(a, b, acc[fj], 0, 0, 0);
      }
    }
    // swds_l = <Gamma_l, C>
    float part = 0.f;
#pragma unroll
    for (int fj = 0; fj < 8; ++fj)
#pragma unroll
      for (int r = 0; r < 4; ++r)
        part += acc[fj][r] * C[(cr + r) * NSEQ + (fj << 4) + cc];
#pragma unroll
    for (int off = 32; off >= 1; off >>= 1) part += __shfl_xor(part, off);
    if (lane == 0) red[w] = part;
    __syncthreads();             // red ready; aux/PvT reads all done
    float swds = ((red[0] + red[1]) + (red[2] + red[3]))
               + ((red[4] + red[5]) + (red[6] + red[7]));
    if (swds < m_run) {
      float sc = __expf(-10.f * (m_run - swds));   // first iter: 0
      Z = Z * sc + 1.f;
#pragma unroll
      for (int b = 0; b < 8; ++b) att[b] = att[b] * sc + acc[b];
      m_run = swds;
    } else {
      float e = __expf(-10.f * (swds - m_run));
      Z += e;
#pragma unroll
      for (int b = 0; b < 8; ++b) att[b] += e * acc[b];
    }
    if (q == 0) {   // load next l's state (aux reads finished; barrier at loop top)
      const float* stg = ws + OFF_ST + (size_t)(bh * 64 + lc * 2 + 1) * 768;
      aux[t] = stg[t];
      if (t < 256) aux[t + 512] = stg[t + 512];
    }
  }
  if (HALFP) {
    _Float16* P = (_Float16*)(ws + OFF_PART) + (size_t)blk * (NSEQ * NSEQ);
#pragma unroll
    for (int fj = 0; fj < 8; ++fj)
#pragma unroll
      for (int r = 0; r < 4; ++r)
        P[(cr + r) * NSEQ + (fj << 4) + cc] = (_Float16)att[fj][r];
  } else {
    float* P = ws + OFF_PART + (size_t)blk * (NSEQ * NSEQ);
#pragma unroll
    for (int fj = 0; fj < 8; ++fj)
#pragma unroll
      for (int r = 0; r < 4; ++r)
        P[(cr + r) * NSEQ + (fj << 4) + cc] = att[fj][r];
  }
  if (t == 0) {
    ws[OFF_SWDS + blk * 2]     = m_run;
    ws[OFF_SWDS + blk * 2 + 1] = Z;
  }
}

// ---------------- fallback phase kernels (unchanged math) ----------------
__global__ __launch_bounds__(512, 4) void k_phase1_fb(float* __restrict__ ws) {
  extern __shared__ char smem[];
  _Float16* PuT = (_Float16*)smem;
  _Float16* PvT = PuT + NSEQ * SPAD;
  float* s_   = (float*)(PvT + NSEQ * SPAD);
  float* ss_  = s_ + 128;
  float* inv_ = ss_ + 128;
  float* den4 = inv_ + 128;
  float* red  = den4 + 512;
  const int bhl = blockIdx.x, bh = bhl >> 6, l = bhl & 63;
  const int t = threadIdx.x, w = t >> 6, lane = t & 63;
  build_PT(ws + OFF_X + (size_t)bh * NSEQ * DIMH + l, PuT, s_, ss_, inv_, den4, t);
  build_PT(ws + OFF_Y + (size_t)bh * NSEQ * DIMH + l, PvT, s_, ss_, inv_, den4, t);
  f32x4 acc[8];
#pragma unroll
  for (int b = 0; b < 8; ++b) acc[b] = 0;
  const int r0 = w << 4;
#pragma unroll
  for (int kc = 0; kc < 4; ++kc) {
    const int k0 = kc << 5;
    f16x8 a0 = fragPT(PuT, r0, k0, lane);
#pragma unroll
    for (int fj = 0; fj < 8; ++fj) {
      f16x8 b = fragPT(PvT, fj << 4, k0, lane);
      acc[fj] = __builtin_amdgcn_mfma_f32_16x16x32_f16(a0, b, acc[fj], 0, 0, 0);
    }
  }
  const float* C = ws + OFF_COST + (size_t)bh * NSEQ * NSEQ;
  const int cr = r0 + ((lane >> 4) << 2), cc = lane & 15;
  float part = 0.f;
#pragma unroll
  for (int fj = 0; fj < 8; ++fj)
#pragma unroll
    for (int r = 0; r < 4; ++r)
      part += acc[fj][r] * C[(cr + r) * NSEQ + (fj << 4) + cc];
#pragma unroll
  for (int off = 32; off >= 1; off >>= 1) part += __shfl_xor(part, off);
  if (lane == 0) red[w] = part;
  __syncthreads();
  if (t == 0) {
    float s = 0;
#pragma unroll
    for (int i = 0; i < 8; ++i) s += red[i];
    ws[OFF_SWDS + bhl] = s;
  }
}

__global__ void k_weights(float* __restrict__ ws) {
  const int bh = blockIdx.x;
  const int l = threadIdx.x;
  float v = ws[OFF_SWDS + bh * 64 + l];
  float mn = v;
#pragma unroll
  for (int off = 32; off >= 1; off >>= 1) mn = fminf(mn, __shfl_xor(mn, off));
  float e = __expf(-10.f * (v - mn));
  float sum = e;
#pragma unroll
  for (int off = 32; off >= 1; off >>= 1) sum += __shfl_xor(sum, off);
  ws[OFF_W + bh * 64 + l] = e / sum;
}

__global__ __launch_bounds__(512, 4) void k_phase2_fb(float* __restrict__ ws, float* __restrict__ attn) {
  extern __shared__ char smem[];
  _Float16* PuT = (_Float16*)smem;
  _Float16* PvT = PuT + NSEQ * SPAD;
  float* s_   = (float*)(PvT + NSEQ * SPAD);
  float* ss_  = s_ + 128;
  float* inv_ = ss_ + 128;
  float* den4 = inv_ + 128;
  const int blk = blockIdx.x, bh = blk >> 4, lc = blk & 15;
  const int t = threadIdx.x, w = t >> 6, lane = t & 63;
  const int r0 = w << 4;
  f32x4 att[8];
#pragma unroll
  for (int b = 0; b < 8; ++b) att[b] = 0;
  for (int q = 0; q < 4; ++q) {
    const int l = (lc << 2) + q;
    const float wl = ws[OFF_W + bh * 64 + l];
    build_PT(ws + OFF_X + (size_t)bh * NSEQ * DIMH + l, PuT, s_, ss_, inv_, den4, t);
    build_PT(ws + OFF_Y + (size_t)bh * NSEQ * DIMH + l, PvT, s_, ss_, inv_, den4, t);
    f32x4 acc[8];
#pragma unroll
    for (int b = 0; b < 8; ++b) acc[b] = 0;
#pragma unroll
    for (int kc = 0; kc < 4; ++kc) {
      const int k0 = kc << 5;
      f16x8 a0 = fragPT(PuT, r0, k0, lane);
#pragma unroll
      for (int fj = 0; fj < 8; ++fj) {
        f16x8 b = fragPT(PvT, fj << 4, k0, lane);
        acc[fj] = __builtin_amdgcn_mfma_f32_16x16x32_f16(a0, b, acc[fj], 0, 0, 0);
      }
    }
#pragma unroll
    for (int b = 0; b < 8; ++b) att[b] += wl * acc[b];
  }
  float* A = attn + (size_t)bh * NSEQ * NSEQ;
  const int cr = r0 + ((lane >> 4) << 2), cc = lane & 15;
#pragma unroll
  for (int fj = 0; fj < 8; ++fj)
#pragma unroll
    for (int r = 0; r < 4; ++r)
      atomicAdd(&A[(cr + r) * NSEQ + (fj << 4) + cc], att[fj][r]);
}

// ---- K_avr: online-combine 32 partials -> attn, then AV matmul; writes f16 ohh ----
template <bool HALFP>
__global__ __launch_bounds__(256) void k_avr(float* __restrict__ ws, float* __restrict__ attn) {
  __shared__ float Vs[128 * 64];
  __shared__ float As[16 * 128];
  __shared__ float F[32];
  __shared__ float Zinv_s;
  const int bh = blockIdx.x, g = blockIdx.y;
  const int t = threadIdx.x;
  for (int c = t; c < 8192; c += 256) Vs[c] = ws[OFF_V + (size_t)bh * 8192 + c];
  if (t < 64) {   // lane-parallel combine of 32 (m_b, Z_b): xor<32 stays in 32-halves
    const int p = t & 31;
    float mb = ws[OFF_SWDS + (bh * 32 + p) * 2];
    float zb = ws[OFF_SWDS + (bh * 32 + p) * 2 + 1];
    float m = mb;
#pragma unroll
    for (int off = 16; off >= 1; off >>= 1) m = fminf(m, __shfl_xor(m, off));
    float f = __expf(-10.f * (mb - m));
    float fz = f * zb;
    float Zt = fz;
#pragma unroll
    for (int off = 16; off >= 1; off >>= 1) Zt += __shfl_xor(fz, off), fz = Zt;
    if (t < 32) F[t] = f;
    if (t == 0) Zinv_s = 1.f / Zt;
  }
  __syncthreads();
  const float zi = Zinv_s;
  for (int c = t; c < 2048; c += 256) {
    float s = 0.f;
    if (HALFP) {
      const _Float16* P = (const _Float16*)(ws + OFF_PART);
#pragma unroll
      for (int p = 0; p < 32; ++p)
        s += F[p] * (float)P[((size_t)(bh * 32 + p)) * 16384 + (size_t)g * 2048 + c];
    } else {
#pragma unroll
      for (int p = 0; p < 32; ++p)
        s += F[p] * ws[OFF_PART + ((size_t)(bh * 32 + p)) * 16384 + (size_t)g * 2048 + c];
    }
    s *= zi;
    As[c] = s;
    attn[(size_t)bh * 16384 + (size_t)g * 2048 + c] = s;
  }
  __syncthreads();
  const int i = t >> 4, dq = t & 15;
  f32x4 acc = {};
  const float* arow = &As[i * 128];
  for (int j = 0; j < 128; ++j) {
    float a = arow[j];
    f32x4 v = ((const f32x4*)&Vs[j * 64])[dq];
    acc += a * v;
  }
  const int b = bh >> 3, h = bh & 7, n = g * 16 + i;
  const size_t obase = ((size_t)(b * NSEQ + n)) * DMODEL + h * DIMH + (dq << 2);
  _Float16* oh16 = (_Float16*)(ws + OFF_XT + 131072) + obase;
  f16x4 hh;
  hh[0] = (_Float16)acc[0]; hh[1] = (_Float16)acc[1];
  hh[2] = (_Float16)acc[2]; hh[3] = (_Float16)acc[3];
  *(f16x4*)oh16 = hh;
}

// ---- K6a fallback: oh = attn @ V ----
__global__ __launch_bounds__(256) void k_av(const float* __restrict__ attn, float* __restrict__ ws) {
  __shared__ float Vs[128 * 64];
  __shared__ float As[16 * 128];
  const int bh = blockIdx.x, g = blockIdx.y;
  const int t = threadIdx.x;
  const float* Ag = attn + (size_t)bh * 16384 + (size_t)g * 16 * 128;
  const float* Vg = ws + OFF_V + (size_t)bh * 8192;
  for (int c = t; c < 2048; c += 256) As[c] = Ag[c];
  for (int c = t; c < 8192; c += 256) Vs[c] = Vg[c];
  __syncthreads();
  const int i = t >> 4, dq = t & 15;
  f32x4 acc = {};
  const float* arow = &As[i * 128];
  for (int j = 0; j < 128; ++j) {
    float a = arow[j];
    f32x4 v = ((const f32x4*)&Vs[j * 64])[dq];
    acc += a * v;
  }
  const int b = bh >> 3, h = bh & 7, n = g * 16 + i;
  const size_t obase = ((size_t)(b * NSEQ + n)) * DMODEL + h * DIMH + (dq << 2);
  float* o = ws + OFF_OH + obase;
  *(f32x4*)o = acc;
}

// ---- K6b fast: out = ohh @ wout^T + b_out (wout cvt fused) ----
__global__ __launch_bounds__(256) void k_out_f(const float* __restrict__ ws_c,
                                               const float* __restrict__ wout,
                                               const float* __restrict__ bout,
                                               float* __restrict__ out) {
  __shared__ _Float16 Ah[64][72];
  __shared__ _Float16 Bh[64][72];
  const _Float16* ah = (const _Float16*)(ws_c + OFF_XT + 131072);
  const int r0 = blockIdx.x * 64, c0 = blockIdx.y * 64;
  const int t = threadIdx.x, w = t >> 6, lane = t & 63;
  const int srow = t >> 2, sk = (t & 3) << 4;
  f32x4 acc[4] = {};
  for (int kc = 0; kc < 512; kc += 64) {
    __syncthreads();
    {
      *(f16x8*)&Ah[srow][sk]     = *(const f16x8*)&ah[(size_t)(r0 + srow) * 512 + kc + sk];
      *(f16x8*)&Ah[srow][sk + 8] = *(const f16x8*)&ah[(size_t)(r0 + srow) * 512 + kc + sk + 8];
      const float* bp = &wout[(size_t)(c0 + srow) * 512 + kc + sk];
      f32x4 b0 = *(const f32x4*)&bp[0], b1 = *(const f32x4*)&bp[4];
      f32x4 b2 = *(const f32x4*)&bp[8], b3 = *(const f32x4*)&bp[12];
      *(f16x8*)&Bh[srow][sk]     = cvt8(b0, b1);
      *(f16x8*)&Bh[srow][sk + 8] = cvt8(b2, b3);
    }
    __syncthreads();
#pragma unroll
    for (int k0 = 0; k0 < 64; k0 += 32) {
      f16x8 a = *(const f16x8*)&Ah[(w << 4) + (lane & 15)][k0 + ((lane >> 4) << 3)];
#pragma unroll
      for (int fj = 0; fj < 4; ++fj) {
        f16x8 b = *(const f16x8*)&Bh[(fj << 4) + (lane & 15)][k0 + ((lane >> 4) << 3)];
        acc[fj] = __builtin_amdgcn_mfma_f32_16x16x32_f16(a, b, acc[fj], 0, 0, 0);
      }
    }
  }
  const int rowb = r0 + (w << 4) + ((lane >> 4) << 2);
#pragma unroll
  for (int fj = 0; fj < 4; ++fj) {
    const int c = c0 + (fj << 4) + (lane & 15);
    const float bb = bout[c];
#pragma unroll
    for (int r = 0; r < 4; ++r)
      out[(size_t)(rowb + r) * 512 + c] = acc[fj][r] + bb;
  }
}

// ---------------- K6b-fallback: f32 VALU out ----------------
__global__ __launch_bounds__(256) void k_out(const float* __restrict__ oh,
                                             const float* __restrict__ wout,
                                             const float* __restrict__ bout,
                                             float* __restrict__ out) {
  __shared__ float as_[64][65];
  __shared__ float bs_[64][65];
  const int r0 = blockIdx.x * 64, c0 = blockIdx.y * 64;
  const int t = threadIdx.x;
  const int tr = (t >> 4) << 2, tc = (t & 15) << 2;
  float acc[4][4] = {};
  for (int k0 = 0; k0 < 512; k0 += 64) {
    for (int idx = t; idx < 64 * 64; idx += 256) {
      int i = idx >> 6, j = idx & 63;
      as_[i][j] = oh[(size_t)(r0 + i) * 512 + k0 + j];
      bs_[i][j] = wout[(size_t)(c0 + i) * 512 + k0 + j];
    }
    __syncthreads();
    for (int kk = 0; kk < 64; ++kk) {
      float a[4], b[4];
#pragma unroll
      for (int u = 0; u < 4; ++u) { a[u] = as_[tr + u][kk]; b[u] = bs_[tc + u][kk]; }
#pragma unroll
      for (int u = 0; u < 4; ++u)
#pragma unroll
        for (int w = 0; w < 4; ++w) acc[u][w] += a[u] * b[w];
    }
    __syncthreads();
  }
#pragma unroll
  for (int u = 0; u < 4; ++u)
#pragma unroll
    for (int w = 0; w < 4; ++w)
      out[(size_t)(r0 + tr + u) * 512 + c0 + tc + w] = acc[u][w] + bout[c0 + tc + w];
}

extern "C" void kernel_launch(void* const* d_in, const int* in_sizes, int n_in,
                              void* d_out, int out_size, void* d_ws, size_t ws_size,
                              hipStream_t stream) {
  (void)in_sizes; (void)n_in; (void)out_size;
  const float* x    = (const float*)d_in[0];
  const float* wqkv = (const float*)d_in[1];
  const float* wout = (const float*)d_in[2];
  const float* bout = (const float*)d_in[3];
  float* out  = (float*)d_out;           // [4,128,512]
  float* attn = out + 262144;            // [4,8,128,128]
  float* ws   = (float*)d_ws;

  const size_t need_f16 = (size_t)END_PART * 4;                         // 48.25 MB
  const size_t need_f32 = ((size_t)OFF_PART + 1024ull * 16384) * 4;     // 81.8 MB

  if (ws_size >= need_f16) {
    k_qkv_f<<<dim3(8, 24), 256, 0, stream>>>(x, wqkv, ws);
    k_cost<<<dim3(32, 8), 256, 0, stream>>>(ws);
    k_sortden<<<4096, 256, 0, stream>>>(ws);
    if (ws_size >= need_f32) {
      k_pf<false><<<1024, 512, PF_SMEM, stream>>>(ws);
      k_avr<false><<<dim3(32, 8), 256, 0, stream>>>(ws, attn);
    } else {
      k_pf<true><<<1024, 512, PF_SMEM, stream>>>(ws);
      k_avr<true><<<dim3(32, 8), 256, 0, stream>>>(ws, attn);
    }
    k_out_f<<<dim3(8, 8), 256, 0, stream>>>(ws, wout, bout, out);
  } else {
    k_qkv<<<dim3(8, 24), 256, 0, stream>>>(x, wqkv, ws, 0);
    k_cost<<<dim3(32, 8), 256, 0, stream>>>(ws);
    k_phase1_fb<<<2048, 512, PH_SMEM, stream>>>(ws);
    k_weights<<<32, 64, 0, stream>>>(ws);
    hipMemsetAsync(attn, 0, 524288 * sizeof(float), stream);
    k_phase2_fb<<<512, 512, PH_SMEM, stream>>>(ws, attn);
    k_av<<<dim3(32, 8), 256, 0, stream>>>(attn, ws);
    k_out<<<dim3(8, 8), 256, 0, stream>>>(ws + OFF_OH, wout, bout, out);
  }
}

// Round 12
// 139.763 us; speedup vs baseline: 1.5573x; 1.5573x over previous
//
#include <hip/hip_runtime.h>
#include <math.h>

typedef _Float16 f16x8 __attribute__((ext_vector_type(8)));
typedef _Float16 f16x4 __attribute__((ext_vector_type(4)));
typedef float f32x4 __attribute__((ext_vector_type(4)));

#define NSEQ   128
#define DIMH   64
#define NHEAD  8
#define DMODEL 512
#define SCALE  0.125f      // 64^-0.5
#define SPAD   136         // f16 elems per PT row (272B stride: 2-way/quarter = free)

// ws layout (float offsets)
#define OFF_X    0          // [32][128][64]
#define OFF_Y    262144
#define OFF_V    524288
#define OFF_COST 786432     // [32][128][128]
#define OFF_SWDS 1310720    // fast: [512][2] (m_b, Z_b); fallback: [32][64] swds
#define OFF_W    1312768    // [32][64] (fallback only)
#define OFF_OH   1314816    // [4*128][512] f32 oh (fallback path)
#define OFF_XT   1576960    // [32][64][128]  X^T per head (dead after k_sortden)
#define OFF_YT   1839104    // [32][64][128]
#define OFF_ST   2101248    // [4096][384]  state: s(128), ss(128), inv(128) per build
#define OFF_PART 3674112    // [512][128][128] f32 online partials A_b
#define END_PART 12062720   // 48.25 MB total (confirmed available since R6)
// f16 alias: ohh = XT+131072 (written by k_avr after XT dead, read by k_out_f)

// k_pf LDS: PvT (34816B) + aux[4][768] (12288B) + red (32B) = 47136B
#define PF_SMEM  (NSEQ * SPAD * 2 + (4 * 768 + 8) * 4)
#define PH_SMEM  (2 * NSEQ * SPAD * 2 + (128 * 3 + 512 + 8) * 4) // fallback

__device__ __forceinline__ f16x8 cvt8(f32x4 a, f32x4 b) {
  f16x8 h;
  h[0] = (_Float16)a[0]; h[1] = (_Float16)a[1]; h[2] = (_Float16)a[2]; h[3] = (_Float16)a[3];
  h[4] = (_Float16)b[0]; h[5] = (_Float16)b[1]; h[6] = (_Float16)b[2]; h[7] = (_Float16)b[3];
  return h;
}

// ------- K1: qkv = x @ w_qkv^T via MFMA, f32->f16 cvt fused into staging -------
__global__ __launch_bounds__(256) void k_qkv_f(const float* __restrict__ x,
                                               const float* __restrict__ wq,
                                               float* __restrict__ ws) {
  __shared__ _Float16 Ah[64][72];
  __shared__ _Float16 Bh[64][72];
  const int r0 = blockIdx.x * 64, c0 = blockIdx.y * 64;
  const int t = threadIdx.x, w = t >> 6, lane = t & 63;
  const int srow = t >> 2, sk = (t & 3) << 4;
  f32x4 acc[4] = {};
  for (int kc = 0; kc < 512; kc += 64) {
    __syncthreads();
    {
      const float* ap = &x[(size_t)(r0 + srow) * 512 + kc + sk];
      const float* bp = &wq[(size_t)(c0 + srow) * 512 + kc + sk];
      f32x4 a0 = *(const f32x4*)&ap[0], a1 = *(const f32x4*)&ap[4];
      f32x4 a2 = *(const f32x4*)&ap[8], a3 = *(const f32x4*)&ap[12];
      f32x4 b0 = *(const f32x4*)&bp[0], b1 = *(const f32x4*)&bp[4];
      f32x4 b2 = *(const f32x4*)&bp[8], b3 = *(const f32x4*)&bp[12];
      *(f16x8*)&Ah[srow][sk]     = cvt8(a0, a1);
      *(f16x8*)&Ah[srow][sk + 8] = cvt8(a2, a3);
      *(f16x8*)&Bh[srow][sk]     = cvt8(b0, b1);
      *(f16x8*)&Bh[srow][sk + 8] = cvt8(b2, b3);
    }
    __syncthreads();
#pragma unroll
    for (int k0 = 0; k0 < 64; k0 += 32) {
      f16x8 a = *(const f16x8*)&Ah[(w << 4) + (lane & 15)][k0 + ((lane >> 4) << 3)];
#pragma unroll
      for (int fj = 0; fj < 4; ++fj) {
        f16x8 b = *(const f16x8*)&Bh[(fj << 4) + (lane & 15)][k0 + ((lane >> 4) << 3)];
        acc[fj] = __builtin_amdgcn_mfma_f32_16x16x32_f16(a, b, acc[fj], 0, 0, 0);
      }
    }
  }
  float* X = ws + OFF_X; float* Y = ws + OFF_Y; float* V = ws + OFF_V;
  float* XT = ws + OFF_XT; float* YT = ws + OFF_YT;
  const int rowb = r0 + (w << 4) + ((lane >> 4) << 2);
#pragma unroll
  for (int fj = 0; fj < 4; ++fj) {
    const int c = c0 + (fj << 4) + (lane & 15);
    const int which = c >> 9, cc = c & 511, h = cc >> 6, d = cc & 63;
#pragma unroll
    for (int r = 0; r < 4; ++r) {
      const int rr = rowb + r, bb = rr >> 7, n = rr & 127;
      const int bh = bb * NHEAD + h;
      float val = acc[fj][r];
      size_t dst = ((size_t)bh * NSEQ + n) * DIMH + d;
      size_t dstT = ((size_t)bh * DIMH + d) * NSEQ + n;
      if (which == 0)      { X[dst] = val * SCALE; XT[dstT] = val * SCALE; }
      else if (which == 1) { Y[dst] = val * SCALE; YT[dstT] = val * SCALE; }
      else                 V[dst] = val;
    }
  }
}

// ---------------- K1-fallback: f32 VALU qkv ----------------
__global__ __launch_bounds__(256) void k_qkv(const float* __restrict__ x,
                                             const float* __restrict__ wqkv,
                                             float* __restrict__ ws, int wrT) {
  __shared__ float xs[64][65];
  __shared__ float wsm[64][65];
  const int r0 = blockIdx.x * 64;
  const int c0 = blockIdx.y * 64;
  const int t = threadIdx.x;
  const int tr = (t >> 4) << 2;
  const int tc = (t & 15) << 2;
  float acc[4][4] = {};
  for (int k0 = 0; k0 < 512; k0 += 64) {
    for (int idx = t; idx < 64 * 64; idx += 256) {
      int i = idx >> 6, j = idx & 63;
      xs[i][j]  = x[(size_t)(r0 + i) * 512 + k0 + j];
      wsm[i][j] = wqkv[(size_t)(c0 + i) * 512 + k0 + j];
    }
    __syncthreads();
    for (int kk = 0; kk < 64; ++kk) {
      float a[4], b[4];
#pragma unroll
      for (int u = 0; u < 4; ++u) { a[u] = xs[tr + u][kk]; b[u] = wsm[tc + u][kk]; }
#pragma unroll
      for (int u = 0; u < 4; ++u)
#pragma unroll
        for (int w = 0; w < 4; ++w) acc[u][w] += a[u] * b[w];
    }
    __syncthreads();
  }
  float* X = ws + OFF_X; float* Y = ws + OFF_Y; float* V = ws + OFF_V;
  float* XT = ws + OFF_XT; float* YT = ws + OFF_YT;
#pragma unroll
  for (int u = 0; u < 4; ++u) {
    int r = r0 + tr + u; int b = r >> 7, n = r & 127;
#pragma unroll
    for (int w = 0; w < 4; ++w) {
      int c = c0 + tc + w;
      float val = acc[u][w];
      int which = c >> 9;
      int cc = c & 511;
      int h = cc >> 6, d = cc & 63;
      int bh = b * NHEAD + h;
      size_t dst = ((size_t)bh * NSEQ + n) * DIMH + d;
      size_t dstT = ((size_t)bh * DIMH + d) * NSEQ + n;
      if (which == 0)      { X[dst] = val * SCALE; if (wrT) XT[dstT] = val * SCALE; }
      else if (which == 1) { Y[dst] = val * SCALE; if (wrT) YT[dstT] = val * SCALE; }
      else                 V[dst] = val;
    }
  }
}

// ---------------- K2: cost[bh][i][j] = ||X_i - Y_j||_2 ----------------
__global__ __launch_bounds__(256) void k_cost(float* __restrict__ ws) {
  __shared__ float Ys[128 * 64];
  __shared__ float Xs[16 * 64];
  __shared__ float xx[16], yy[128];
  const int bh = blockIdx.x, g = blockIdx.y;
  const int t = threadIdx.x;
  const float* Xg = ws + OFF_X + (size_t)bh * NSEQ * DIMH + (size_t)g * 16 * DIMH;
  const float* Yg = ws + OFF_Y + (size_t)bh * NSEQ * DIMH;
  for (int c = t; c < 1024; c += 256) Xs[c] = Xg[c];
  for (int c = t; c < 8192; c += 256) Ys[c] = Yg[c];
  __syncthreads();
  if (t < 128) {
    float s = 0;
    const f32x4* y4 = (const f32x4*)&Ys[t * 64];
#pragma unroll
    for (int d = 0; d < 16; ++d) { f32x4 v = y4[d]; s += v[0]*v[0]+v[1]*v[1]+v[2]*v[2]+v[3]*v[3]; }
    yy[t] = s;
  } else if (t < 144) {
    int i = t - 128; float s = 0;
    const f32x4* x4 = (const f32x4*)&Xs[i * 64];
#pragma unroll
    for (int d = 0; d < 16; ++d) { f32x4 v = x4[d]; s += v[0]*v[0]+v[1]*v[1]+v[2]*v[2]+v[3]*v[3]; }
    xx[i] = s;
  }
  __syncthreads();
  const int i = t >> 4, j0 = (t & 15) << 3;
  f32x4 xr[16];
#pragma unroll
  for (int d = 0; d < 16; ++d) xr[d] = ((const f32x4*)&Xs[i * 64])[d];
  const float xxi = xx[i];
  float* C = ws + OFF_COST + (size_t)bh * NSEQ * NSEQ + (size_t)(g * 16 + i) * NSEQ + j0;
  f32x4 o0, o1;
#pragma unroll
  for (int jj = 0; jj < 8; ++jj) {
    const f32x4* y4 = (const f32x4*)&Ys[(j0 + jj) * 64];
    float dot = 0;
#pragma unroll
    for (int d = 0; d < 16; ++d) {
      f32x4 xv = xr[d], yv = y4[d];
      dot += xv[0]*yv[0] + xv[1]*yv[1] + xv[2]*yv[2] + xv[3]*yv[3];
    }
    float sq = xxi + yy[j0 + jj] - 2.f * dot;
    float cv = sqrtf(fmaxf(sq, 0.f));
    if (jj < 4) o0[jj] = cv; else o1[jj - 4] = cv;
  }
  *(f32x4*)&C[0] = o0;
  *(f32x4*)&C[4] = o1;
}

// -------- K_sortden: per (bh,l,uv) compute state s(128), ss(128), inv(128) --------
__global__ __launch_bounds__(256) void k_sortden(float* __restrict__ ws) {
  __shared__ float s_lds[128], ss_lds[128], den2[256];
  const int bid = blockIdx.x;            // (bh*64 + l)*2 + uv
  const int t = threadIdx.x;
  const float* src = ws + ((bid & 1) ? OFF_YT : OFF_XT) + (size_t)(bid >> 1) * NSEQ;
  float* st = ws + OFF_ST + (size_t)bid * 384;
  if (t < 128) s_lds[t] = src[t];
  __syncthreads();
  if (t < 128) {
    const float v = s_lds[t];
    int rank = 0;
#pragma unroll 4
    for (int m = 0; m < NSEQ; m += 4) {
      f32x4 u = *(const f32x4*)&s_lds[m];
#pragma unroll
      for (int j = 0; j < 4; ++j)
        rank += (u[j] > v) || (u[j] == v && (m + j) < t);
    }
    ss_lds[rank] = v;   // descending sorted
  }
  __syncthreads();
  {
    const int k = t & 127, half = t >> 7;
    const float sk = ss_lds[k];
    const float* sb = s_lds + (half << 6);
    float sum = 0.f;
#pragma unroll 4
    for (int m = 0; m < 64; m += 4) {
      f32x4 u = *(const f32x4*)&sb[m];
#pragma unroll
      for (int j = 0; j < 4; ++j) {
        float d = u[j] - sk;
        sum += __expf(-1000.f * d * d);
      }
    }
    den2[(half << 7) + k] = sum;
  }
  __syncthreads();
  if (t < 128) {
    st[t]       = s_lds[t];
    st[128 + t] = ss_lds[t];
    st[256 + t] = 1.f / (den2[t] + den2[128 + t]);
  }
}

// Generate PT entries from LDS state (512 threads; no internal barrier).
// Mapping i=t&127, k0=(t>>7)*32: ss/inv reads are wave-uniform broadcasts
// (conflict-free); PT writes at 272B stride spread across bank quads.
__device__ __forceinline__ void gen_PT(const float* __restrict__ st,
                                       _Float16* __restrict__ PT, int t) {
  const int i = t & 127, k0 = (t >> 7) << 5;
  const float si = st[i];
  const float* ssp = st + 128 + k0;
  const float* ivp = st + 256 + k0;
#pragma unroll
  for (int kb = 0; kb < 32; kb += 8) {
    f32x4 sv0 = *(const f32x4*)&ssp[kb];
    f32x4 sv1 = *(const f32x4*)&ssp[kb + 4];
    f32x4 iv0 = *(const f32x4*)&ivp[kb];
    f32x4 iv1 = *(const f32x4*)&ivp[kb + 4];
    f16x8 pk;
#pragma unroll
    for (int j = 0; j < 4; ++j) {
      float d0 = si - sv0[j];
      float d1 = si - sv1[j];
      pk[j]     = (_Float16)(__expf(-1000.f * d0 * d0) * iv0[j]);
      pk[j + 4] = (_Float16)(__expf(-1000.f * d1 * d1) * iv1[j]);
    }
    *reinterpret_cast<f16x8*>(&PT[i * SPAD + k0 + kb]) = pk;
  }
}

// Per-lane A-fragment gen: 8 entries for row (r0+lane&15), k..k+8
__device__ __forceinline__ f16x8 gen_Afrag(float si, const float* __restrict__ ss,
                                           const float* __restrict__ iv, int k) {
  f32x4 s0 = *(const f32x4*)&ss[k], s1 = *(const f32x4*)&ss[k + 4];
  f32x4 i0 = *(const f32x4*)&iv[k], i1 = *(const f32x4*)&iv[k + 4];
  f16x8 a;
#pragma unroll
  for (int j = 0; j < 4; ++j) {
    float d0 = si - s0[j];
    float d1 = si - s1[j];
    a[j]     = (_Float16)(__expf(-1000.f * d0 * d0) * i0[j]);
    a[j + 4] = (_Float16)(__expf(-1000.f * d1 * d1) * i1[j]);
  }
  return a;
}

// Fallback: full in-kernel build, 512 threads, internal barriers.
__device__ void build_PT(const float* __restrict__ col, _Float16* __restrict__ PT,
                         float* s_, float* ss_, float* inv_, float* den4, int t) {
  if (t < NSEQ) s_[t] = col[(size_t)t * DIMH];
  __syncthreads();
  if (t < NSEQ) {
    const float v = s_[t];
    int rank = 0;
#pragma unroll 4
    for (int m = 0; m < NSEQ; m += 4) {
      f32x4 u = *(const f32x4*)&s_[m];
#pragma unroll
      for (int j = 0; j < 4; ++j)
        rank += (u[j] > v) || (u[j] == v && (m + j) < t);
    }
    ss_[rank] = v;
  }
  __syncthreads();
  {
    const int k = t & 127, q = t >> 7;
    const float sk = ss_[k];
    const float* sb = s_ + (q << 5);
    float sum = 0.f;
#pragma unroll 4
    for (int m = 0; m < 32; m += 4) {
      f32x4 u = *(const f32x4*)&sb[m];
#pragma unroll
      for (int j = 0; j < 4; ++j) {
        float d = u[j] - sk;
        sum += __expf(-1000.f * d * d);
      }
    }
    den4[(q << 7) + k] = sum;
  }
  __syncthreads();
  if (t < NSEQ)
    inv_[t] = 1.f / (den4[t] + den4[128 + t] + den4[256 + t] + den4[384 + t]);
  __syncthreads();
  {
    const int i = t >> 2, k0 = (t & 3) << 5;
    const float si = s_[i];
#pragma unroll
    for (int kb = 0; kb < 32; kb += 8) {
      f32x4 sv0 = *(const f32x4*)&ss_[k0 + kb];
      f32x4 sv1 = *(const f32x4*)&ss_[k0 + kb + 4];
      f32x4 iv0 = *(const f32x4*)&inv_[k0 + kb];
      f32x4 iv1 = *(const f32x4*)&inv_[k0 + kb + 4];
      f16x8 pk;
#pragma unroll
      for (int j = 0; j < 4; ++j) {
        float d0 = si - sv0[j];
        float d1 = si - sv1[j];
        pk[j]     = (_Float16)(__expf(-1000.f * d0 * d0) * iv0[j]);
        pk[j + 4] = (_Float16)(__expf(-1000.f * d1 * d1) * iv1[j]);
      }
      *reinterpret_cast<f16x8*>(&PT[i * SPAD + k0 + kb]) = pk;
    }
  }
  __syncthreads();
}

__device__ __forceinline__ f16x8 fragPT(const _Float16* PT, int baserow, int k0, int lane) {
  return *reinterpret_cast<const f16x8*>(
      &PT[(baserow + (lane & 15)) * SPAD + k0 + ((lane >> 4) << 3)]);
}

// ---- K_pf: fused phases — per block (bh, 4 l's): Gamma via MFMA, swds dot,
// ---- ONLINE softmax accumulation. Aux preloaded for all 4 l's; gen_PT(l+1)
// ---- overlaps the C-dot's global-load latency. 2 barriers per l. ----
__global__ __launch_bounds__(512, 4) void k_pf(float* __restrict__ ws) {
  extern __shared__ char smem[];
  _Float16* PvT = (_Float16*)smem;
  float* aux = (float*)(PvT + NSEQ * SPAD);   // [4][768]
  float* red = aux + 4 * 768;                 // 8
  const int blk = blockIdx.x, bh = blk >> 4, lc = blk & 15;  // 4 l's per block
  const int t = threadIdx.x, w = t >> 6, lane = t & 63;
  const int r0 = w << 4;
  const int kq = (lane >> 4) << 3;
  const float* C = ws + OFF_COST + (size_t)bh * NSEQ * NSEQ;
  const int cr = r0 + ((lane >> 4) << 2), cc = lane & 15;
  f32x4 att[8];
#pragma unroll
  for (int b = 0; b < 8; ++b) att[b] = 0;
  float m_run = 3.0e38f, Z = 0.f;
  {   // preload state for all 4 l's (3072 floats, coalesced)
    const float* stg = ws + OFF_ST + (size_t)(bh * 64 + lc * 4) * 768;
    for (int i = t; i < 3072; i += 512) aux[i] = stg[i];
  }
  __syncthreads();
  gen_PT(aux + 384, PvT, t);   // PvT for l0
  __syncthreads();
  for (int q = 0; q < 4; ++q) {
    const float* a_st = aux + q * 768;
    const float si = a_st[r0 + (lane & 15)];
    const float* ssu = a_st + 128;
    const float* ivu = a_st + 256;
    f32x4 acc[8];
#pragma unroll
    for (int b = 0; b < 8; ++b) acc[b] = 0;
#pragma unroll
    for (int kc = 0; kc < 4; ++kc) {
      const int k0 = kc << 5;
      f16x8 a = gen_Afrag(si, ssu, ivu, k0 + kq);
#pragma unroll
      for (int fj = 0; fj < 8; ++fj) {
        f16x8 b = fragPT(PvT, fj << 4, k0, lane);
        acc[fj] = __builtin_amdgcn_mfma_f32_16x16x32_f16(a, b, acc[fj], 0, 0, 0);
      }
    }
    __syncthreads();   // all PvT reads done -> safe to regenerate
    // C-dot loads (long latency) interleave with next-l exp generation (ILP)
    float part = 0.f;
#pragma unroll
    for (int fj = 0; fj < 8; ++fj)
#pragma unroll
      for (int r = 0; r < 4; ++r)
        part += acc[fj][r] * C[(cr + r) * NSEQ + (fj << 4) + cc];
    if (q < 3) gen_PT(aux + (q + 1) * 768 + 384, PvT, t);
#pragma unroll
    for (int off = 32; off >= 1; off >>= 1) part += __shfl_xor(part, off);
    if (lane == 0) red[w] = part;
    __syncthreads();   // red ready AND PvT(next) written
    float swds = ((red[0] + red[1]) + (red[2] + red[3]))
               + ((red[4] + red[5]) + (red[6] + red[7]));
    if (swds < m_run) {
      float sc = __expf(-10.f * (m_run - swds));   // first iter: exp(-inf)=0
      Z = Z * sc + 1.f;
#pragma unroll
      for (int b = 0; b < 8; ++b) att[b] = att[b] * sc + acc[b];
      m_run = swds;
    } else {
      float e = __expf(-10.f * (swds - m_run));
      Z += e;
#pragma unroll
      for (int b = 0; b < 8; ++b) att[b] += e * acc[b];
    }
  }
  float* P = ws + OFF_PART + (size_t)blk * (NSEQ * NSEQ);
#pragma unroll
  for (int fj = 0; fj < 8; ++fj)
#pragma unroll
    for (int r = 0; r < 4; ++r)
      P[(cr + r) * NSEQ + (fj << 4) + cc] = att[fj][r];
  if (t == 0) {
    ws[OFF_SWDS + blk * 2]     = m_run;
    ws[OFF_SWDS + blk * 2 + 1] = Z;
  }
}

// ---------------- fallback phase kernels (unchanged math) ----------------
__global__ __launch_bounds__(512, 4) void k_phase1_fb(float* __restrict__ ws) {
  extern __shared__ char smem[];
  _Float16* PuT = (_Float16*)smem;
  _Float16* PvT = PuT + NSEQ * SPAD;
  float* s_   = (float*)(PvT + NSEQ * SPAD);
  float* ss_  = s_ + 128;
  float* inv_ = ss_ + 128;
  float* den4 = inv_ + 128;
  float* red  = den4 + 512;
  const int bhl = blockIdx.x, bh = bhl >> 6, l = bhl & 63;
  const int t = threadIdx.x, w = t >> 6, lane = t & 63;
  build_PT(ws + OFF_X + (size_t)bh * NSEQ * DIMH + l, PuT, s_, ss_, inv_, den4, t);
  build_PT(ws + OFF_Y + (size_t)bh * NSEQ * DIMH + l, PvT, s_, ss_, inv_, den4, t);
  f32x4 acc[8];
#pragma unroll
  for (int b = 0; b < 8; ++b) acc[b] = 0;
  const int r0 = w << 4;
#pragma unroll
  for (int kc = 0; kc < 4; ++kc) {
    const int k0 = kc << 5;
    f16x8 a0 = fragPT(PuT, r0, k0, lane);
#pragma unroll
    for (int fj = 0; fj < 8; ++fj) {
      f16x8 b = fragPT(PvT, fj << 4, k0, lane);
      acc[fj] = __builtin_amdgcn_mfma_f32_16x16x32_f16(a0, b, acc[fj], 0, 0, 0);
    }
  }
  const float* C = ws + OFF_COST + (size_t)bh * NSEQ * NSEQ;
  const int cr = r0 + ((lane >> 4) << 2), cc = lane & 15;
  float part = 0.f;
#pragma unroll
  for (int fj = 0; fj < 8; ++fj)
#pragma unroll
    for (int r = 0; r < 4; ++r)
      part += acc[fj][r] * C[(cr + r) * NSEQ + (fj << 4) + cc];
#pragma unroll
  for (int off = 32; off >= 1; off >>= 1) part += __shfl_xor(part, off);
  if (lane == 0) red[w] = part;
  __syncthreads();
  if (t == 0) {
    float s = 0;
#pragma unroll
    for (int i = 0; i < 8; ++i) s += red[i];
    ws[OFF_SWDS + bhl] = s;
  }
}

__global__ void k_weights(float* __restrict__ ws) {
  const int bh = blockIdx.x;
  const int l = threadIdx.x;
  float v = ws[OFF_SWDS + bh * 64 + l];
  float mn = v;
#pragma unroll
  for (int off = 32; off >= 1; off >>= 1) mn = fminf(mn, __shfl_xor(mn, off));
  float e = __expf(-10.f * (v - mn));
  float sum = e;
#pragma unroll
  for (int off = 32; off >= 1; off >>= 1) sum += __shfl_xor(sum, off);
  ws[OFF_W + bh * 64 + l] = e / sum;
}

__global__ __launch_bounds__(512, 4) void k_phase2_fb(float* __restrict__ ws, float* __restrict__ attn) {
  extern __shared__ char smem[];
  _Float16* PuT = (_Float16*)smem;
  _Float16* PvT = PuT + NSEQ * SPAD;
  float* s_   = (float*)(PvT + NSEQ * SPAD);
  float* ss_  = s_ + 128;
  float* inv_ = ss_ + 128;
  float* den4 = inv_ + 128;
  const int blk = blockIdx.x, bh = blk >> 4, lc = blk & 15;
  const int t = threadIdx.x, w = t >> 6, lane = t & 63;
  const int r0 = w << 4;
  f32x4 att[8];
#pragma unroll
  for (int b = 0; b < 8; ++b) att[b] = 0;
  for (int q = 0; q < 4; ++q) {
    const int l = (lc << 2) + q;
    const float wl = ws[OFF_W + bh * 64 + l];
    build_PT(ws + OFF_X + (size_t)bh * NSEQ * DIMH + l, PuT, s_, ss_, inv_, den4, t);
    build_PT(ws + OFF_Y + (size_t)bh * NSEQ * DIMH + l, PvT, s_, ss_, inv_, den4, t);
    f32x4 acc[8];
#pragma unroll
    for (int b = 0; b < 8; ++b) acc[b] = 0;
#pragma unroll
    for (int kc = 0; kc < 4; ++kc) {
      const int k0 = kc << 5;
      f16x8 a0 = fragPT(PuT, r0, k0, lane);
#pragma unroll
      for (int fj = 0; fj < 8; ++fj) {
        f16x8 b = fragPT(PvT, fj << 4, k0, lane);
        acc[fj] = __builtin_amdgcn_mfma_f32_16x16x32_f16(a0, b, acc[fj], 0, 0, 0);
      }
    }
#pragma unroll
    for (int b = 0; b < 8; ++b) att[b] += wl * acc[b];
  }
  float* A = attn + (size_t)bh * NSEQ * NSEQ;
  const int cr = r0 + ((lane >> 4) << 2), cc = lane & 15;
#pragma unroll
  for (int fj = 0; fj < 8; ++fj)
#pragma unroll
    for (int r = 0; r < 4; ++r)
      atomicAdd(&A[(cr + r) * NSEQ + (fj << 4) + cc], att[fj][r]);
}

// ---- K_avr: online-combine 16 partials -> attn, then AV matmul; writes f16 ohh ----
__global__ __launch_bounds__(256) void k_avr(float* __restrict__ ws, float* __restrict__ attn) {
  __shared__ float Vs[128 * 64];
  __shared__ float As[16 * 128];
  __shared__ float F[16];
  __shared__ float Zinv_s;
  const int bh = blockIdx.x, g = blockIdx.y;
  const int t = threadIdx.x;
  for (int c = t; c < 8192; c += 256) Vs[c] = ws[OFF_V + (size_t)bh * 8192 + c];
  if (t < 32) {   // lane-parallel combine of 16 (m_b, Z_b); xor<=8 stays in 16-halves
    const int p = t & 15;
    float mb = ws[OFF_SWDS + (bh * 16 + p) * 2];
    float zb = ws[OFF_SWDS + (bh * 16 + p) * 2 + 1];
    float m = mb;
#pragma unroll
    for (int off = 8; off >= 1; off >>= 1) m = fminf(m, __shfl_xor(m, off));
    float f = __expf(-10.f * (mb - m));
    float s = f * zb;
#pragma unroll
    for (int off = 8; off >= 1; off >>= 1) s += __shfl_xor(s, off);
    if (t < 16) F[t] = f;
    if (t == 0) Zinv_s = 1.f / s;
  }
  __syncthreads();
  const float zi = Zinv_s;
  for (int c = t; c < 2048; c += 256) {
    float s = 0.f;
#pragma unroll
    for (int p = 0; p < 16; ++p)
      s += F[p] * ws[OFF_PART + ((size_t)(bh * 16 + p)) * 16384 + (size_t)g * 2048 + c];
    s *= zi;
    As[c] = s;
    attn[(size_t)bh * 16384 + (size_t)g * 2048 + c] = s;
  }
  __syncthreads();
  const int i = t >> 4, dq = t & 15;
  f32x4 acc = {};
  const float* arow = &As[i * 128];
  for (int j = 0; j < 128; ++j) {
    float a = arow[j];
    f32x4 v = ((const f32x4*)&Vs[j * 64])[dq];
    acc += a * v;
  }
  const int b = bh >> 3, h = bh & 7, n = g * 16 + i;
  const size_t obase = ((size_t)(b * NSEQ + n)) * DMODEL + h * DIMH + (dq << 2);
  _Float16* oh16 = (_Float16*)(ws + OFF_XT + 131072) + obase;
  f16x4 hh;
  hh[0] = (_Float16)acc[0]; hh[1] = (_Float16)acc[1];
  hh[2] = (_Float16)acc[2]; hh[3] = (_Float16)acc[3];
  *(f16x4*)oh16 = hh;
}

// ---- K6a fallback: oh = attn @ V ----
__global__ __launch_bounds__(256) void k_av(const float* __restrict__ attn, float* __restrict__ ws) {
  __shared__ float Vs[128 * 64];
  __shared__ float As[16 * 128];
  const int bh = blockIdx.x, g = blockIdx.y;
  const int t = threadIdx.x;
  const float* Ag = attn + (size_t)bh * 16384 + (size_t)g * 16 * 128;
  const float* Vg = ws + OFF_V + (size_t)bh * 8192;
  for (int c = t; c < 2048; c += 256) As[c] = Ag[c];
  for (int c = t; c < 8192; c += 256) Vs[c] = Vg[c];
  __syncthreads();
  const int i = t >> 4, dq = t & 15;
  f32x4 acc = {};
  const float* arow = &As[i * 128];
  for (int j = 0; j < 128; ++j) {
    float a = arow[j];
    f32x4 v = ((const f32x4*)&Vs[j * 64])[dq];
    acc += a * v;
  }
  const int b = bh >> 3, h = bh & 7, n = g * 16 + i;
  const size_t obase = ((size_t)(b * NSEQ + n)) * DMODEL + h * DIMH + (dq << 2);
  float* o = ws + OFF_OH + obase;
  *(f32x4*)o = acc;
}

// ---- K6b fast: out = ohh @ wout^T + b_out (wout cvt fused) ----
__global__ __launch_bounds__(256) void k_out_f(const float* __restrict__ ws_c,
                                               const float* __restrict__ wout,
                                               const float* __restrict__ bout,
                                               float* __restrict__ out) {
  __shared__ _Float16 Ah[64][72];
  __shared__ _Float16 Bh[64][72];
  const _Float16* ah = (const _Float16*)(ws_c + OFF_XT + 131072);
  const int r0 = blockIdx.x * 64, c0 = blockIdx.y * 64;
  const int t = threadIdx.x, w = t >> 6, lane = t & 63;
  const int srow = t >> 2, sk = (t & 3) << 4;
  f32x4 acc[4] = {};
  for (int kc = 0; kc < 512; kc += 64) {
    __syncthreads();
    {
      *(f16x8*)&Ah[srow][sk]     = *(const f16x8*)&ah[(size_t)(r0 + srow) * 512 + kc + sk];
      *(f16x8*)&Ah[srow][sk + 8] = *(const f16x8*)&ah[(size_t)(r0 + srow) * 512 + kc + sk + 8];
      const float* bp = &wout[(size_t)(c0 + srow) * 512 + kc + sk];
      f32x4 b0 = *(const f32x4*)&bp[0], b1 = *(const f32x4*)&bp[4];
      f32x4 b2 = *(const f32x4*)&bp[8], b3 = *(const f32x4*)&bp[12];
      *(f16x8*)&Bh[srow][sk]     = cvt8(b0, b1);
      *(f16x8*)&Bh[srow][sk + 8] = cvt8(b2, b3);
    }
    __syncthreads();
#pragma unroll
    for (int k0 = 0; k0 < 64; k0 += 32) {
      f16x8 a = *(const f16x8*)&Ah[(w << 4) + (lane & 15)][k0 + ((lane >> 4) << 3)];
#pragma unroll
      for (int fj = 0; fj < 4; ++fj) {
        f16x8 b = *(const f16x8*)&Bh[(fj << 4) + (lane & 15)][k0 + ((lane >> 4) << 3)];
        acc[fj] = __builtin_amdgcn_mfma_f32_16x16x32_f16(a, b, acc[fj], 0, 0, 0);
      }
    }
  }
  const int rowb = r0 + (w << 4) + ((lane >> 4) << 2);
#pragma unroll
  for (int fj = 0; fj < 4; ++fj) {
    const int c = c0 + (fj << 4) + (lane & 15);
    const float bb = bout[c];
#pragma unroll
    for (int r = 0; r < 4; ++r)
      out[(size_t)(rowb + r) * 512 + c] = acc[fj][r] + bb;
  }
}

// ---------------- K6b-fallback: f32 VALU out ----------------
__global__ __launch_bounds__(256) void k_out(const float* __restrict__ oh,
                                             const float* __restrict__ wout,
                                             const float* __restrict__ bout,
                                             float* __restrict__ out) {
  __shared__ float as_[64][65];
  __shared__ float bs_[64][65];
  const int r0 = blockIdx.x * 64, c0 = blockIdx.y * 64;
  const int t = threadIdx.x;
  const int tr = (t >> 4) << 2, tc = (t & 15) << 2;
  float acc[4][4] = {};
  for (int k0 = 0; k0 < 512; k0 += 64) {
    for (int idx = t; idx < 64 * 64; idx += 256) {
      int i = idx >> 6, j = idx & 63;
      as_[i][j] = oh[(size_t)(r0 + i) * 512 + k0 + j];
      bs_[i][j] = wout[(size_t)(c0 + i) * 512 + k0 + j];
    }
    __syncthreads();
    for (int kk = 0; kk < 64; ++kk) {
      float a[4], b[4];
#pragma unroll
      for (int u = 0; u < 4; ++u) { a[u] = as_[tr + u][kk]; b[u] = bs_[tc + u][kk]; }
#pragma unroll
      for (int u = 0; u < 4; ++u)
#pragma unroll
        for (int w = 0; w < 4; ++w) acc[u][w] += a[u] * b[w];
    }
    __syncthreads();
  }
#pragma unroll
  for (int u = 0; u < 4; ++u)
#pragma unroll
    for (int w = 0; w < 4; ++w)
      out[(size_t)(r0 + tr + u) * 512 + c0 + tc + w] = acc[u][w] + bout[c0 + tc + w];
}

extern "C" void kernel_launch(void* const* d_in, const int* in_sizes, int n_in,
                              void* d_out, int out_size, void* d_ws, size_t ws_size,
                              hipStream_t stream) {
  (void)in_sizes; (void)n_in; (void)out_size;
  const float* x    = (const float*)d_in[0];
  const float* wqkv = (const float*)d_in[1];
  const float* wout = (const float*)d_in[2];
  const float* bout = (const float*)d_in[3];
  float* out  = (float*)d_out;           // [4,128,512]
  float* attn = out + 262144;            // [4,8,128,128]
  float* ws   = (float*)d_ws;

  const bool fast = ws_size >= (size_t)END_PART * 4;   // 48.25 MB, confirmed since R6

  if (fast) {
    k_qkv_f<<<dim3(8, 24), 256, 0, stream>>>(x, wqkv, ws);
    k_cost<<<dim3(32, 8), 256, 0, stream>>>(ws);
    k_sortden<<<4096, 256, 0, stream>>>(ws);
    k_pf<<<512, 512, PF_SMEM, stream>>>(ws);
    k_avr<<<dim3(32, 8), 256, 0, stream>>>(ws, attn);
    k_out_f<<<dim3(8, 8), 256, 0, stream>>>(ws, wout, bout, out);
  } else {
    k_qkv<<<dim3(8, 24), 256, 0, stream>>>(x, wqkv, ws, 0);
    k_cost<<<dim3(32, 8), 256, 0, stream>>>(ws);
    k_phase1_fb<<<2048, 512, PH_SMEM, stream>>>(ws);
    k_weights<<<32, 64, 0, stream>>>(ws);
    hipMemsetAsync(attn, 0, 524288 * sizeof(float), stream);
    k_phase2_fb<<<512, 512, PH_SMEM, stream>>>(ws, attn);
    k_av<<<dim3(32, 8), 256, 0, stream>>>(attn, ws);
    k_out<<<dim3(8, 8), 256, 0, stream>>>(ws + OFF_OH, wout, bout, out);
  }
}

// Round 13
// 120.204 us; speedup vs baseline: 1.8107x; 1.1627x over previous
//
#include <hip/hip_runtime.h>
#include <math.h>

typedef _Float16 f16x8 __attribute__((ext_vector_type(8)));
typedef _Float16 f16x4 __attribute__((ext_vector_type(4)));
typedef float f32x4 __attribute__((ext_vector_type(4)));

#define NSEQ   128
#define DIMH   64
#define NHEAD  8
#define DMODEL 512
#define SCALE  0.125f      // 64^-0.5
#define SPAD   136         // f16 elems per PT row (272B stride: 2-way/quarter = free)

// ws layout (float offsets)
#define OFF_X    0          // [32][128][64]
#define OFF_Y    262144
#define OFF_V    524288
#define OFF_COST 786432     // [32][128][128]
#define OFF_SWDS 1310720    // fast: [512][2] (m_b, Z_b); fallback: [32][64] swds
#define OFF_W    1312768    // [32][64] (fallback only)
#define OFF_OH   1314816    // [4*128][512] f32 oh (fallback path)
#define OFF_XT   1576960    // [32][64][128]  X^T per head (dead after k_sortden)
#define OFF_YT   1839104    // [32][64][128]
#define OFF_ST   2101248    // [4096][384]  state: s(128), ss(128), inv(128) per build
#define OFF_PART 3674112    // [512][128][128] f32 online partials A_b
#define END_PART 12062720   // 48.25 MB total (confirmed available since R6)
// f16 alias: ohh = XT+131072 (written by k_avr after XT dead, read by k_out_f)

// k_pf LDS: PvT (34816B) + aux[4][768] (12288B) + red (32B) = 47136B -> 3 blocks/CU
#define PF_SMEM  (NSEQ * SPAD * 2 + (4 * 768 + 8) * 4)
#define PH_SMEM  (2 * NSEQ * SPAD * 2 + (128 * 3 + 512 + 8) * 4) // fallback

__device__ __forceinline__ f16x8 cvt8(f32x4 a, f32x4 b) {
  f16x8 h;
  h[0] = (_Float16)a[0]; h[1] = (_Float16)a[1]; h[2] = (_Float16)a[2]; h[3] = (_Float16)a[3];
  h[4] = (_Float16)b[0]; h[5] = (_Float16)b[1]; h[6] = (_Float16)b[2]; h[7] = (_Float16)b[3];
  return h;
}

// ------- K1: qkv = x @ w_qkv^T via MFMA, f32->f16 cvt fused into staging -------
__global__ __launch_bounds__(256) void k_qkv_f(const float* __restrict__ x,
                                               const float* __restrict__ wq,
                                               float* __restrict__ ws) {
  __shared__ _Float16 Ah[64][72];
  __shared__ _Float16 Bh[64][72];
  const int r0 = blockIdx.x * 64, c0 = blockIdx.y * 64;
  const int t = threadIdx.x, w = t >> 6, lane = t & 63;
  const int srow = t >> 2, sk = (t & 3) << 4;
  f32x4 acc[4] = {};
  for (int kc = 0; kc < 512; kc += 64) {
    __syncthreads();
    {
      const float* ap = &x[(size_t)(r0 + srow) * 512 + kc + sk];
      const float* bp = &wq[(size_t)(c0 + srow) * 512 + kc + sk];
      f32x4 a0 = *(const f32x4*)&ap[0], a1 = *(const f32x4*)&ap[4];
      f32x4 a2 = *(const f32x4*)&ap[8], a3 = *(const f32x4*)&ap[12];
      f32x4 b0 = *(const f32x4*)&bp[0], b1 = *(const f32x4*)&bp[4];
      f32x4 b2 = *(const f32x4*)&bp[8], b3 = *(const f32x4*)&bp[12];
      *(f16x8*)&Ah[srow][sk]     = cvt8(a0, a1);
      *(f16x8*)&Ah[srow][sk + 8] = cvt8(a2, a3);
      *(f16x8*)&Bh[srow][sk]     = cvt8(b0, b1);
      *(f16x8*)&Bh[srow][sk + 8] = cvt8(b2, b3);
    }
    __syncthreads();
#pragma unroll
    for (int k0 = 0; k0 < 64; k0 += 32) {
      f16x8 a = *(const f16x8*)&Ah[(w << 4) + (lane & 15)][k0 + ((lane >> 4) << 3)];
#pragma unroll
      for (int fj = 0; fj < 4; ++fj) {
        f16x8 b = *(const f16x8*)&Bh[(fj << 4) + (lane & 15)][k0 + ((lane >> 4) << 3)];
        acc[fj] = __builtin_amdgcn_mfma_f32_16x16x32_f16(a, b, acc[fj], 0, 0, 0);
      }
    }
  }
  float* X = ws + OFF_X; float* Y = ws + OFF_Y; float* V = ws + OFF_V;
  float* XT = ws + OFF_XT; float* YT = ws + OFF_YT;
  const int rowb = r0 + (w << 4) + ((lane >> 4) << 2);
#pragma unroll
  for (int fj = 0; fj < 4; ++fj) {
    const int c = c0 + (fj << 4) + (lane & 15);
    const int which = c >> 9, cc = c & 511, h = cc >> 6, d = cc & 63;
#pragma unroll
    for (int r = 0; r < 4; ++r) {
      const int rr = rowb + r, bb = rr >> 7, n = rr & 127;
      const int bh = bb * NHEAD + h;
      float val = acc[fj][r];
      size_t dst = ((size_t)bh * NSEQ + n) * DIMH + d;
      size_t dstT = ((size_t)bh * DIMH + d) * NSEQ + n;
      if (which == 0)      { X[dst] = val * SCALE; XT[dstT] = val * SCALE; }
      else if (which == 1) { Y[dst] = val * SCALE; YT[dstT] = val * SCALE; }
      else                 V[dst] = val;
    }
  }
}

// ---------------- K1-fallback: f32 VALU qkv ----------------
__global__ __launch_bounds__(256) void k_qkv(const float* __restrict__ x,
                                             const float* __restrict__ wqkv,
                                             float* __restrict__ ws, int wrT) {
  __shared__ float xs[64][65];
  __shared__ float wsm[64][65];
  const int r0 = blockIdx.x * 64;
  const int c0 = blockIdx.y * 64;
  const int t = threadIdx.x;
  const int tr = (t >> 4) << 2;
  const int tc = (t & 15) << 2;
  float acc[4][4] = {};
  for (int k0 = 0; k0 < 512; k0 += 64) {
    for (int idx = t; idx < 64 * 64; idx += 256) {
      int i = idx >> 6, j = idx & 63;
      xs[i][j]  = x[(size_t)(r0 + i) * 512 + k0 + j];
      wsm[i][j] = wqkv[(size_t)(c0 + i) * 512 + k0 + j];
    }
    __syncthreads();
    for (int kk = 0; kk < 64; ++kk) {
      float a[4], b[4];
#pragma unroll
      for (int u = 0; u < 4; ++u) { a[u] = xs[tr + u][kk]; b[u] = wsm[tc + u][kk]; }
#pragma unroll
      for (int u = 0; u < 4; ++u)
#pragma unroll
        for (int w = 0; w < 4; ++w) acc[u][w] += a[u] * b[w];
    }
    __syncthreads();
  }
  float* X = ws + OFF_X; float* Y = ws + OFF_Y; float* V = ws + OFF_V;
  float* XT = ws + OFF_XT; float* YT = ws + OFF_YT;
#pragma unroll
  for (int u = 0; u < 4; ++u) {
    int r = r0 + tr + u; int b = r >> 7, n = r & 127;
#pragma unroll
    for (int w = 0; w < 4; ++w) {
      int c = c0 + tc + w;
      float val = acc[u][w];
      int which = c >> 9;
      int cc = c & 511;
      int h = cc >> 6, d = cc & 63;
      int bh = b * NHEAD + h;
      size_t dst = ((size_t)bh * NSEQ + n) * DIMH + d;
      size_t dstT = ((size_t)bh * DIMH + d) * NSEQ + n;
      if (which == 0)      { X[dst] = val * SCALE; if (wrT) XT[dstT] = val * SCALE; }
      else if (which == 1) { Y[dst] = val * SCALE; if (wrT) YT[dstT] = val * SCALE; }
      else                 V[dst] = val;
    }
  }
}

// ---------------- K2: cost[bh][i][j] = ||X_i - Y_j||_2 ----------------
__global__ __launch_bounds__(256) void k_cost(float* __restrict__ ws) {
  __shared__ float Ys[128 * 64];
  __shared__ float Xs[16 * 64];
  __shared__ float xx[16], yy[128];
  const int bh = blockIdx.x, g = blockIdx.y;
  const int t = threadIdx.x;
  const float* Xg = ws + OFF_X + (size_t)bh * NSEQ * DIMH + (size_t)g * 16 * DIMH;
  const float* Yg = ws + OFF_Y + (size_t)bh * NSEQ * DIMH;
  for (int c = t; c < 1024; c += 256) Xs[c] = Xg[c];
  for (int c = t; c < 8192; c += 256) Ys[c] = Yg[c];
  __syncthreads();
  if (t < 128) {
    float s = 0;
    const f32x4* y4 = (const f32x4*)&Ys[t * 64];
#pragma unroll
    for (int d = 0; d < 16; ++d) { f32x4 v = y4[d]; s += v[0]*v[0]+v[1]*v[1]+v[2]*v[2]+v[3]*v[3]; }
    yy[t] = s;
  } else if (t < 144) {
    int i = t - 128; float s = 0;
    const f32x4* x4 = (const f32x4*)&Xs[i * 64];
#pragma unroll
    for (int d = 0; d < 16; ++d) { f32x4 v = x4[d]; s += v[0]*v[0]+v[1]*v[1]+v[2]*v[2]+v[3]*v[3]; }
    xx[i] = s;
  }
  __syncthreads();
  const int i = t >> 4, j0 = (t & 15) << 3;
  f32x4 xr[16];
#pragma unroll
  for (int d = 0; d < 16; ++d) xr[d] = ((const f32x4*)&Xs[i * 64])[d];
  const float xxi = xx[i];
  float* C = ws + OFF_COST + (size_t)bh * NSEQ * NSEQ + (size_t)(g * 16 + i) * NSEQ + j0;
  f32x4 o0, o1;
#pragma unroll
  for (int jj = 0; jj < 8; ++jj) {
    const f32x4* y4 = (const f32x4*)&Ys[(j0 + jj) * 64];
    float dot = 0;
#pragma unroll
    for (int d = 0; d < 16; ++d) {
      f32x4 xv = xr[d], yv = y4[d];
      dot += xv[0]*yv[0] + xv[1]*yv[1] + xv[2]*yv[2] + xv[3]*yv[3];
    }
    float sq = xxi + yy[j0 + jj] - 2.f * dot;
    float cv = sqrtf(fmaxf(sq, 0.f));
    if (jj < 4) o0[jj] = cv; else o1[jj - 4] = cv;
  }
  *(f32x4*)&C[0] = o0;
  *(f32x4*)&C[4] = o1;
}

// -------- K_sortden: per (bh,l,uv) compute state s(128), ss(128), inv(128) --------
__global__ __launch_bounds__(256) void k_sortden(float* __restrict__ ws) {
  __shared__ float s_lds[128], ss_lds[128], den2[256];
  const int bid = blockIdx.x;            // (bh*64 + l)*2 + uv
  const int t = threadIdx.x;
  const float* src = ws + ((bid & 1) ? OFF_YT : OFF_XT) + (size_t)(bid >> 1) * NSEQ;
  float* st = ws + OFF_ST + (size_t)bid * 384;
  if (t < 128) s_lds[t] = src[t];
  __syncthreads();
  if (t < 128) {
    const float v = s_lds[t];
    int rank = 0;
#pragma unroll 4
    for (int m = 0; m < NSEQ; m += 4) {
      f32x4 u = *(const f32x4*)&s_lds[m];
#pragma unroll
      for (int j = 0; j < 4; ++j)
        rank += (u[j] > v) || (u[j] == v && (m + j) < t);
    }
    ss_lds[rank] = v;   // descending sorted
  }
  __syncthreads();
  {
    const int k = t & 127, half = t >> 7;
    const float sk = ss_lds[k];
    const float* sb = s_lds + (half << 6);
    float sum = 0.f;
#pragma unroll 4
    for (int m = 0; m < 64; m += 4) {
      f32x4 u = *(const f32x4*)&sb[m];
#pragma unroll
      for (int j = 0; j < 4; ++j) {
        float d = u[j] - sk;
        sum += __expf(-1000.f * d * d);
      }
    }
    den2[(half << 7) + k] = sum;
  }
  __syncthreads();
  if (t < 128) {
    st[t]       = s_lds[t];
    st[128 + t] = ss_lds[t];
    st[256 + t] = 1.f / (den2[t] + den2[128 + t]);
  }
}

// Generate PT entries from LDS state (512 threads; no internal barrier).
// Mapping i=t&127, k0=(t>>7)*32: ss/inv reads are wave-uniform broadcasts
// (conflict-free); PT writes at 272B stride spread across bank quads.
__device__ __forceinline__ void gen_PT(const float* __restrict__ st,
                                       _Float16* __restrict__ PT, int t) {
  const int i = t & 127, k0 = (t >> 7) << 5;
  const float si = st[i];
  const float* ssp = st + 128 + k0;
  const float* ivp = st + 256 + k0;
#pragma unroll
  for (int kb = 0; kb < 32; kb += 8) {
    f32x4 sv0 = *(const f32x4*)&ssp[kb];
    f32x4 sv1 = *(const f32x4*)&ssp[kb + 4];
    f32x4 iv0 = *(const f32x4*)&ivp[kb];
    f32x4 iv1 = *(const f32x4*)&ivp[kb + 4];
    f16x8 pk;
#pragma unroll
    for (int j = 0; j < 4; ++j) {
      float d0 = si - sv0[j];
      float d1 = si - sv1[j];
      pk[j]     = (_Float16)(__expf(-1000.f * d0 * d0) * iv0[j]);
      pk[j + 4] = (_Float16)(__expf(-1000.f * d1 * d1) * iv1[j]);
    }
    *reinterpret_cast<f16x8*>(&PT[i * SPAD + k0 + kb]) = pk;
  }
}

// Per-lane A-fragment gen: 8 entries for row (r0+lane&15), k..k+8
__device__ __forceinline__ f16x8 gen_Afrag(float si, const float* __restrict__ ss,
                                           const float* __restrict__ iv, int k) {
  f32x4 s0 = *(const f32x4*)&ss[k], s1 = *(const f32x4*)&ss[k + 4];
  f32x4 i0 = *(const f32x4*)&iv[k], i1 = *(const f32x4*)&iv[k + 4];
  f16x8 a;
#pragma unroll
  for (int j = 0; j < 4; ++j) {
    float d0 = si - s0[j];
    float d1 = si - s1[j];
    a[j]     = (_Float16)(__expf(-1000.f * d0 * d0) * i0[j]);
    a[j + 4] = (_Float16)(__expf(-1000.f * d1 * d1) * i1[j]);
  }
  return a;
}

// Fallback: full in-kernel build, 512 threads, internal barriers.
__device__ void build_PT(const float* __restrict__ col, _Float16* __restrict__ PT,
                         float* s_, float* ss_, float* inv_, float* den4, int t) {
  if (t < NSEQ) s_[t] = col[(size_t)t * DIMH];
  __syncthreads();
  if (t < NSEQ) {
    const float v = s_[t];
    int rank = 0;
#pragma unroll 4
    for (int m = 0; m < NSEQ; m += 4) {
      f32x4 u = *(const f32x4*)&s_[m];
#pragma unroll
      for (int j = 0; j < 4; ++j)
        rank += (u[j] > v) || (u[j] == v && (m + j) < t);
    }
    ss_[rank] = v;
  }
  __syncthreads();
  {
    const int k = t & 127, q = t >> 7;
    const float sk = ss_[k];
    const float* sb = s_ + (q << 5);
    float sum = 0.f;
#pragma unroll 4
    for (int m = 0; m < 32; m += 4) {
      f32x4 u = *(const f32x4*)&sb[m];
#pragma unroll
      for (int j = 0; j < 4; ++j) {
        float d = u[j] - sk;
        sum += __expf(-1000.f * d * d);
      }
    }
    den4[(q << 7) + k] = sum;
  }
  __syncthreads();
  if (t < NSEQ)
    inv_[t] = 1.f / (den4[t] + den4[128 + t] + den4[256 + t] + den4[384 + t]);
  __syncthreads();
  {
    const int i = t >> 2, k0 = (t & 3) << 5;
    const float si = s_[i];
#pragma unroll
    for (int kb = 0; kb < 32; kb += 8) {
      f32x4 sv0 = *(const f32x4*)&ss_[k0 + kb];
      f32x4 sv1 = *(const f32x4*)&ss_[k0 + kb + 4];
      f32x4 iv0 = *(const f32x4*)&inv_[k0 + kb];
      f32x4 iv1 = *(const f32x4*)&inv_[k0 + kb + 4];
      f16x8 pk;
#pragma unroll
      for (int j = 0; j < 4; ++j) {
        float d0 = si - sv0[j];
        float d1 = si - sv1[j];
        pk[j]     = (_Float16)(__expf(-1000.f * d0 * d0) * iv0[j]);
        pk[j + 4] = (_Float16)(__expf(-1000.f * d1 * d1) * iv1[j]);
      }
      *reinterpret_cast<f16x8*>(&PT[i * SPAD + k0 + kb]) = pk;
    }
  }
  __syncthreads();
}

__device__ __forceinline__ f16x8 fragPT(const _Float16* PT, int baserow, int k0, int lane) {
  return *reinterpret_cast<const f16x8*>(
      &PT[(baserow + (lane & 15)) * SPAD + k0 + ((lane >> 4) << 3)]);
}

// ---- K_pf: fused phases — per block (bh, 4 l's): Gamma via MFMA, swds dot,
// ---- ONLINE softmax accumulation. No reg cap (no spill); LDS-bound 3 blocks/CU.
// ---- gen_PT(l+1) runs only after acc is consumed (short live range). ----
__global__ __launch_bounds__(512) void k_pf(float* __restrict__ ws) {
  extern __shared__ char smem[];
  _Float16* PvT = (_Float16*)smem;
  float* aux = (float*)(PvT + NSEQ * SPAD);   // [4][768]
  float* red = aux + 4 * 768;                 // 8
  const int blk = blockIdx.x, bh = blk >> 4, lc = blk & 15;  // 4 l's per block
  const int t = threadIdx.x, w = t >> 6, lane = t & 63;
  const int r0 = w << 4;
  const int kq = (lane >> 4) << 3;
  const float* C = ws + OFF_COST + (size_t)bh * NSEQ * NSEQ;
  const int cr = r0 + ((lane >> 4) << 2), cc = lane & 15;
  f32x4 att[8];
#pragma unroll
  for (int b = 0; b < 8; ++b) att[b] = 0;
  float m_run = 3.0e38f, Z = 0.f;
  {   // preload state for all 4 l's (3072 floats, coalesced)
    const float* stg = ws + OFF_ST + (size_t)(bh * 64 + lc * 4) * 768;
    for (int i = t; i < 3072; i += 512) aux[i] = stg[i];
  }
  __syncthreads();
  gen_PT(aux + 384, PvT, t);   // PvT for l0
  __syncthreads();
  for (int q = 0; q < 4; ++q) {
    const float* a_st = aux + q * 768;
    const float si = a_st[r0 + (lane & 15)];
    const float* ssu = a_st + 128;
    const float* ivu = a_st + 256;
    f32x4 acc[8];
#pragma unroll
    for (int b = 0; b < 8; ++b) acc[b] = 0;
#pragma unroll
    for (int kc = 0; kc < 4; ++kc) {
      const int k0 = kc << 5;
      f16x8 a = gen_Afrag(si, ssu, ivu, k0 + kq);
#pragma unroll
      for (int fj = 0; fj < 8; ++fj) {
        f16x8 b = fragPT(PvT, fj << 4, k0, lane);
        acc[fj] = __builtin_amdgcn_mfma_f32_16x16x32_f16(a, b, acc[fj], 0, 0, 0);
      }
    }
    // swds_l = <Gamma_l, C>
    float part = 0.f;
#pragma unroll
    for (int fj = 0; fj < 8; ++fj)
#pragma unroll
      for (int r = 0; r < 4; ++r)
        part += acc[fj][r] * C[(cr + r) * NSEQ + (fj << 4) + cc];
#pragma unroll
    for (int off = 32; off >= 1; off >>= 1) part += __shfl_xor(part, off);
    if (lane == 0) red[w] = part;
    __syncthreads();   // red ready AND all PvT/aux reads of this iter done
    float swds = ((red[0] + red[1]) + (red[2] + red[3]))
               + ((red[4] + red[5]) + (red[6] + red[7]));
    // online update consumes acc -> acc dead before gen_PT(next)
    if (swds < m_run) {
      float sc = __expf(-10.f * (m_run - swds));   // first iter: exp(-inf)=0
      Z = Z * sc + 1.f;
#pragma unroll
      for (int b = 0; b < 8; ++b) att[b] = att[b] * sc + acc[b];
      m_run = swds;
    } else {
      float e = __expf(-10.f * (swds - m_run));
      Z += e;
#pragma unroll
      for (int b = 0; b < 8; ++b) att[b] += e * acc[b];
    }
    if (q < 3) {
      gen_PT(aux + (q + 1) * 768 + 384, PvT, t);
      __syncthreads();   // PvT(next) ready
    }
  }
  float* P = ws + OFF_PART + (size_t)blk * (NSEQ * NSEQ);
#pragma unroll
  for (int fj = 0; fj < 8; ++fj)
#pragma unroll
    for (int r = 0; r < 4; ++r)
      P[(cr + r) * NSEQ + (fj << 4) + cc] = att[fj][r];
  if (t == 0) {
    ws[OFF_SWDS + blk * 2]     = m_run;
    ws[OFF_SWDS + blk * 2 + 1] = Z;
  }
}

// ---------------- fallback phase kernels (unchanged math) ----------------
__global__ __launch_bounds__(512, 4) void k_phase1_fb(float* __restrict__ ws) {
  extern __shared__ char smem[];
  _Float16* PuT = (_Float16*)smem;
  _Float16* PvT = PuT + NSEQ * SPAD;
  float* s_   = (float*)(PvT + NSEQ * SPAD);
  float* ss_  = s_ + 128;
  float* inv_ = ss_ + 128;
  float* den4 = inv_ + 128;
  float* red  = den4 + 512;
  const int bhl = blockIdx.x, bh = bhl >> 6, l = bhl & 63;
  const int t = threadIdx.x, w = t >> 6, lane = t & 63;
  build_PT(ws + OFF_X + (size_t)bh * NSEQ * DIMH + l, PuT, s_, ss_, inv_, den4, t);
  build_PT(ws + OFF_Y + (size_t)bh * NSEQ * DIMH + l, PvT, s_, ss_, inv_, den4, t);
  f32x4 acc[8];
#pragma unroll
  for (int b = 0; b < 8; ++b) acc[b] = 0;
  const int r0 = w << 4;
#pragma unroll
  for (int kc = 0; kc < 4; ++kc) {
    const int k0 = kc << 5;
    f16x8 a0 = fragPT(PuT, r0, k0, lane);
#pragma unroll
    for (int fj = 0; fj < 8; ++fj) {
      f16x8 b = fragPT(PvT, fj << 4, k0, lane);
      acc[fj] = __builtin_amdgcn_mfma_f32_16x16x32_f16(a0, b, acc[fj], 0, 0, 0);
    }
  }
  const float* C = ws + OFF_COST + (size_t)bh * NSEQ * NSEQ;
  const int cr = r0 + ((lane >> 4) << 2), cc = lane & 15;
  float part = 0.f;
#pragma unroll
  for (int fj = 0; fj < 8; ++fj)
#pragma unroll
    for (int r = 0; r < 4; ++r)
      part += acc[fj][r] * C[(cr + r) * NSEQ + (fj << 4) + cc];
#pragma unroll
  for (int off = 32; off >= 1; off >>= 1) part += __shfl_xor(part, off);
  if (lane == 0) red[w] = part;
  __syncthreads();
  if (t == 0) {
    float s = 0;
#pragma unroll
    for (int i = 0; i < 8; ++i) s += red[i];
    ws[OFF_SWDS + bhl] = s;
  }
}

__global__ void k_weights(float* __restrict__ ws) {
  const int bh = blockIdx.x;
  const int l = threadIdx.x;
  float v = ws[OFF_SWDS + bh * 64 + l];
  float mn = v;
#pragma unroll
  for (int off = 32; off >= 1; off >>= 1) mn = fminf(mn, __shfl_xor(mn, off));
  float e = __expf(-10.f * (v - mn));
  float sum = e;
#pragma unroll
  for (int off = 32; off >= 1; off >>= 1) sum += __shfl_xor(sum, off);
  ws[OFF_W + bh * 64 + l] = e / sum;
}

__global__ __launch_bounds__(512, 4) void k_phase2_fb(float* __restrict__ ws, float* __restrict__ attn) {
  extern __shared__ char smem[];
  _Float16* PuT = (_Float16*)smem;
  _Float16* PvT = PuT + NSEQ * SPAD;
  float* s_   = (float*)(PvT + NSEQ * SPAD);
  float* ss_  = s_ + 128;
  float* inv_ = ss_ + 128;
  float* den4 = inv_ + 128;
  const int blk = blockIdx.x, bh = blk >> 4, lc = blk & 15;
  const int t = threadIdx.x, w = t >> 6, lane = t & 63;
  const int r0 = w << 4;
  f32x4 att[8];
#pragma unroll
  for (int b = 0; b < 8; ++b) att[b] = 0;
  for (int q = 0; q < 4; ++q) {
    const int l = (lc << 2) + q;
    const float wl = ws[OFF_W + bh * 64 + l];
    build_PT(ws + OFF_X + (size_t)bh * NSEQ * DIMH + l, PuT, s_, ss_, inv_, den4, t);
    build_PT(ws + OFF_Y + (size_t)bh * NSEQ * DIMH + l, PvT, s_, ss_, inv_, den4, t);
    f32x4 acc[8];
#pragma unroll
    for (int b = 0; b < 8; ++b) acc[b] = 0;
#pragma unroll
    for (int kc = 0; kc < 4; ++kc) {
      const int k0 = kc << 5;
      f16x8 a0 = fragPT(PuT, r0, k0, lane);
#pragma unroll
      for (int fj = 0; fj < 8; ++fj) {
        f16x8 b = fragPT(PvT, fj << 4, k0, lane);
        acc[fj] = __builtin_amdgcn_mfma_f32_16x16x32_f16(a0, b, acc[fj], 0, 0, 0);
      }
    }
#pragma unroll
    for (int b = 0; b < 8; ++b) att[b] += wl * acc[b];
  }
  float* A = attn + (size_t)bh * NSEQ * NSEQ;
  const int cr = r0 + ((lane >> 4) << 2), cc = lane & 15;
#pragma unroll
  for (int fj = 0; fj < 8; ++fj)
#pragma unroll
    for (int r = 0; r < 4; ++r)
      atomicAdd(&A[(cr + r) * NSEQ + (fj << 4) + cc], att[fj][r]);
}

// ---- K_avr: online-combine 16 partials -> attn, then AV matmul; writes f16 ohh ----
__global__ __launch_bounds__(256) void k_avr(float* __restrict__ ws, float* __restrict__ attn) {
  __shared__ float Vs[128 * 64];
  __shared__ float As[16 * 128];
  __shared__ float F[16];
  __shared__ float Zinv_s;
  const int bh = blockIdx.x, g = blockIdx.y;
  const int t = threadIdx.x;
  for (int c = t; c < 8192; c += 256) Vs[c] = ws[OFF_V + (size_t)bh * 8192 + c];
  if (t < 32) {   // lane-parallel combine of 16 (m_b, Z_b)
    const int p = t & 15;
    float mb = ws[OFF_SWDS + (bh * 16 + p) * 2];
    float zb = ws[OFF_SWDS + (bh * 16 + p) * 2 + 1];
    float m = mb;
#pragma unroll
    for (int off = 8; off >= 1; off >>= 1) m = fminf(m, __shfl_xor(m, off));
    float f = __expf(-10.f * (mb - m));
    float s = f * zb;
#pragma unroll
    for (int off = 8; off >= 1; off >>= 1) s += __shfl_xor(s, off);
    if (t < 16) F[t] = f;
    if (t == 0) Zinv_s = 1.f / s;
  }
  __syncthreads();
  const float zi = Zinv_s;
  for (int c = t; c < 2048; c += 256) {
    float s = 0.f;
#pragma unroll
    for (int p = 0; p < 16; ++p)
      s += F[p] * ws[OFF_PART + ((size_t)(bh * 16 + p)) * 16384 + (size_t)g * 2048 + c];
    s *= zi;
    As[c] = s;
    attn[(size_t)bh * 16384 + (size_t)g * 2048 + c] = s;
  }
  __syncthreads();
  const int i = t >> 4, dq = t & 15;
  f32x4 acc = {};
  const float* arow = &As[i * 128];
  for (int j = 0; j < 128; ++j) {
    float a = arow[j];
    f32x4 v = ((const f32x4*)&Vs[j * 64])[dq];
    acc += a * v;
  }
  const int b = bh >> 3, h = bh & 7, n = g * 16 + i;
  const size_t obase = ((size_t)(b * NSEQ + n)) * DMODEL + h * DIMH + (dq << 2);
  _Float16* oh16 = (_Float16*)(ws + OFF_XT + 131072) + obase;
  f16x4 hh;
  hh[0] = (_Float16)acc[0]; hh[1] = (_Float16)acc[1];
  hh[2] = (_Float16)acc[2]; hh[3] = (_Float16)acc[3];
  *(f16x4*)oh16 = hh;
}

// ---- K6a fallback: oh = attn @ V ----
__global__ __launch_bounds__(256) void k_av(const float* __restrict__ attn, float* __restrict__ ws) {
  __shared__ float Vs[128 * 64];
  __shared__ float As[16 * 128];
  const int bh = blockIdx.x, g = blockIdx.y;
  const int t = threadIdx.x;
  const float* Ag = attn + (size_t)bh * 16384 + (size_t)g * 16 * 128;
  const float* Vg = ws + OFF_V + (size_t)bh * 8192;
  for (int c = t; c < 2048; c += 256) As[c] = Ag[c];
  for (int c = t; c < 8192; c += 256) Vs[c] = Vg[c];
  __syncthreads();
  const int i = t >> 4, dq = t & 15;
  f32x4 acc = {};
  const float* arow = &As[i * 128];
  for (int j = 0; j < 128; ++j) {
    float a = arow[j];
    f32x4 v = ((const f32x4*)&Vs[j * 64])[dq];
    acc += a * v;
  }
  const int b = bh >> 3, h = bh & 7, n = g * 16 + i;
  const size_t obase = ((size_t)(b * NSEQ + n)) * DMODEL + h * DIMH + (dq << 2);
  float* o = ws + OFF_OH + obase;
  *(f32x4*)o = acc;
}

// ---- K6b fast: out = ohh @ wout^T + b_out (wout cvt fused) ----
__global__ __launch_bounds__(256) void k_out_f(const float* __restrict__ ws_c,
                                               const float* __restrict__ wout,
                                               const float* __restrict__ bout,
                                               float* __restrict__ out) {
  __shared__ _Float16 Ah[64][72];
  __shared__ _Float16 Bh[64][72];
  const _Float16* ah = (const _Float16*)(ws_c + OFF_XT + 131072);
  const int r0 = blockIdx.x * 64, c0 = blockIdx.y * 64;
  const int t = threadIdx.x, w = t >> 6, lane = t & 63;
  const int srow = t >> 2, sk = (t & 3) << 4;
  f32x4 acc[4] = {};
  for (int kc = 0; kc < 512; kc += 64) {
    __syncthreads();
    {
      *(f16x8*)&Ah[srow][sk]     = *(const f16x8*)&ah[(size_t)(r0 + srow) * 512 + kc + sk];
      *(f16x8*)&Ah[srow][sk + 8] = *(const f16x8*)&ah[(size_t)(r0 + srow) * 512 + kc + sk + 8];
      const float* bp = &wout[(size_t)(c0 + srow) * 512 + kc + sk];
      f32x4 b0 = *(const f32x4*)&bp[0], b1 = *(const f32x4*)&bp[4];
      f32x4 b2 = *(const f32x4*)&bp[8], b3 = *(const f32x4*)&bp[12];
      *(f16x8*)&Bh[srow][sk]     = cvt8(b0, b1);
      *(f16x8*)&Bh[srow][sk + 8] = cvt8(b2, b3);
    }
    __syncthreads();
#pragma unroll
    for (int k0 = 0; k0 < 64; k0 += 32) {
      f16x8 a = *(const f16x8*)&Ah[(w << 4) + (lane & 15)][k0 + ((lane >> 4) << 3)];
#pragma unroll
      for (int fj = 0; fj < 4; ++fj) {
        f16x8 b = *(const f16x8*)&Bh[(fj << 4) + (lane & 15)][k0 + ((lane >> 4) << 3)];
        acc[fj] = __builtin_amdgcn_mfma_f32_16x16x32_f16(a, b, acc[fj], 0, 0, 0);
      }
    }
  }
  const int rowb = r0 + (w << 4) + ((lane >> 4) << 2);
#pragma unroll
  for (int fj = 0; fj < 4; ++fj) {
    const int c = c0 + (fj << 4) + (lane & 15);
    const float bb = bout[c];
#pragma unroll
    for (int r = 0; r < 4; ++r)
      out[(size_t)(rowb + r) * 512 + c] = acc[fj][r] + bb;
  }
}

// ---------------- K6b-fallback: f32 VALU out ----------------
__global__ __launch_bounds__(256) void k_out(const float* __restrict__ oh,
                                             const float* __restrict__ wout,
                                             const float* __restrict__ bout,
                                             float* __restrict__ out) {
  __shared__ float as_[64][65];
  __shared__ float bs_[64][65];
  const int r0 = blockIdx.x * 64, c0 = blockIdx.y * 64;
  const int t = threadIdx.x;
  const int tr = (t >> 4) << 2, tc = (t & 15) << 2;
  float acc[4][4] = {};
  for (int k0 = 0; k0 < 512; k0 += 64) {
    for (int idx = t; idx < 64 * 64; idx += 256) {
      int i = idx >> 6, j = idx & 63;
      as_[i][j] = oh[(size_t)(r0 + i) * 512 + k0 + j];
      bs_[i][j] = wout[(size_t)(c0 + i) * 512 + k0 + j];
    }
    __syncthreads();
    for (int kk = 0; kk < 64; ++kk) {
      float a[4], b[4];
#pragma unroll
      for (int u = 0; u < 4; ++u) { a[u] = as_[tr + u][kk]; b[u] = bs_[tc + u][kk]; }
#pragma unroll
      for (int u = 0; u < 4; ++u)
#pragma unroll
        for (int w = 0; w < 4; ++w) acc[u][w] += a[u] * b[w];
    }
    __syncthreads();
  }
#pragma unroll
  for (int u = 0; u < 4; ++u)
#pragma unroll
    for (int w = 0; w < 4; ++w)
      out[(size_t)(r0 + tr + u) * 512 + c0 + tc + w] = acc[u][w] + bout[c0 + tc + w];
}

extern "C" void kernel_launch(void* const* d_in, const int* in_sizes, int n_in,
                              void* d_out, int out_size, void* d_ws, size_t ws_size,
                              hipStream_t stream) {
  (void)in_sizes; (void)n_in; (void)out_size;
  const float* x    = (const float*)d_in[0];
  const float* wqkv = (const float*)d_in[1];
  const float* wout = (const float*)d_in[2];
  const float* bout = (const float*)d_in[3];
  float* out  = (float*)d_out;           // [4,128,512]
  float* attn = out + 262144;            // [4,8,128,128]
  float* ws   = (float*)d_ws;

  const bool fast = ws_size >= (size_t)END_PART * 4;   // 48.25 MB, confirmed since R6

  if (fast) {
    k_qkv_f<<<dim3(8, 24), 256, 0, stream>>>(x, wqkv, ws);
    k_cost<<<dim3(32, 8), 256, 0, stream>>>(ws);
    k_sortden<<<4096, 256, 0, stream>>>(ws);
    k_pf<<<512, 512, PF_SMEM, stream>>>(ws);
    k_avr<<<dim3(32, 8), 256, 0, stream>>>(ws, attn);
    k_out_f<<<dim3(8, 8), 256, 0, stream>>>(ws, wout, bout, out);
  } else {
    k_qkv<<<dim3(8, 24), 256, 0, stream>>>(x, wqkv, ws, 0);
    k_cost<<<dim3(32, 8), 256, 0, stream>>>(ws);
    k_phase1_fb<<<2048, 512, PH_SMEM, stream>>>(ws);
    k_weights<<<32, 64, 0, stream>>>(ws);
    hipMemsetAsync(attn, 0, 524288 * sizeof(float), stream);
    k_phase2_fb<<<512, 512, PH_SMEM, stream>>>(ws, attn);
    k_av<<<dim3(32, 8), 256, 0, stream>>>(attn, ws);
    k_out<<<dim3(8, 8), 256, 0, stream>>>(ws + OFF_OH, wout, bout, out);
  }
}